// Round 12
// baseline (705.238 us; speedup 1.0000x reference)
//
#include <hip/hip_runtime.h>
#include <hip/hip_bf16.h>

typedef __bf16 bf16;
typedef __attribute__((ext_vector_type(8))) bf16 bf16x8;
typedef __attribute__((ext_vector_type(4))) float f32x4;

constexpr int B_   = 16;
constexpr int E_   = 400;
constexpr int R_   = 624;
constexpr int N_   = 1024;
constexpr int HSZ_ = 512;
constexpr int DFF_ = 2048;
constexpr int M_   = B_ * N_;

// global -> LDS direct DMA, 16B per lane (wave-uniform base + lane*16 dest).
__device__ __forceinline__ void glds16(const void* g, void* l) {
    __builtin_amdgcn_global_load_lds((const __attribute__((address_space(1))) void*)g,
                                     (__attribute__((address_space(3))) void*)l,
                                     16, 0, 0);
}

// ---------------------------------------------------------------------------
// R24: all 10 weight transposes merged into ONE launch. Block-range dispatch.
__global__ __launch_bounds__(256) void transpose_all(const float* __restrict__ Wq,
                                                     const float* __restrict__ Wk,
                                                     const float* __restrict__ Wv,
                                                     const float* __restrict__ l1w,
                                                     const float* __restrict__ l2w,
                                                     bf16* __restrict__ WqkvT,
                                                     bf16* __restrict__ L1T,
                                                     bf16* __restrict__ L2T) {
    __shared__ float tile[32][33];
    int id = blockIdx.x;
    const float* in;
    bf16* out;
    int rows, cols, bx, by;
    if (id < 1536) {
        int grp = id >> 8;            // 0..5 = (j, {q,k,v})
        int loc = id & 255;
        bx = loc & 15; by = loc >> 4;
        rows = 512; cols = 512;
        int j = grp / 3, wsel = grp % 3;
        const float* W = (wsel == 0) ? Wq : (wsel == 1) ? Wk : Wv;
        in  = W + j * 262144;
        out = WqkvT + j * 786432 + wsel * 262144;
    } else if (id < 3584) {
        int loc = id - 1536;
        int j = loc >= 1024; loc &= 1023;
        bx = loc & 63; by = loc >> 6;
        rows = 512; cols = 2048;
        in  = l1w + j * 1048576;
        out = L1T + j * 1048576;
    } else {
        int loc = id - 3584;
        int j = loc >= 1024; loc &= 1023;
        bx = loc & 15; by = loc >> 4;
        rows = 2048; cols = 512;
        in  = l2w + j * 1048576;
        out = L2T + j * 1048576;
    }
    int tx = threadIdx.x & 31, ty = threadIdx.x >> 5;   // 32 x 8
    int c0 = bx * 32, r0 = by * 32;
    #pragma unroll
    for (int i = 0; i < 32; i += 8)
        tile[ty + i][tx] = in[(size_t)(r0 + ty + i) * cols + (c0 + tx)];
    __syncthreads();
    #pragma unroll
    for (int i = 0; i < 32; i += 8)
        out[(size_t)(c0 + ty + i) * rows + (r0 + tx)] = (bf16)tile[tx][ty + i];
}

// ---------------------------------------------------------------------------
__global__ __launch_bounds__(256) void pack_adj(const int* __restrict__ adj,
                                                unsigned* __restrict__ adjw) {
    int gid  = blockIdx.x * 4 + (threadIdx.x >> 6);
    int lane = threadIdx.x & 63;
    int w64  = gid & 15;
    int bn   = gid >> 4;
    int v = adj[(size_t)bn * N_ + w64 * 64 + lane];
    unsigned long long mask = __ballot(v != 0);
    if (lane == 0)  adjw[bn * 32 + w64 * 2]     = (unsigned)mask;
    if (lane == 32) adjw[bn * 32 + w64 * 2 + 1] = (unsigned)(mask >> 32);
}

// ---------------------------------------------------------------------------
__global__ __launch_bounds__(256) void build_x(const float* __restrict__ ents,
                                               const int* __restrict__ rels,
                                               const float* __restrict__ renc,
                                               bf16* __restrict__ x) {
    int idx  = blockIdx.x * 256 + threadIdx.x;
    int col8 = (idx & 63) * 8;
    int row  = idx >> 6;
    int b = row >> 10, n = row & 1023;
    const float* src;
    if (n < E_) src = ents + ((size_t)(b * E_ + n)) * HSZ_ + col8;
    else {
        int rt = rels[b * R_ + (n - E_)];
        src = renc + (size_t)rt * HSZ_ + col8;
    }
    float4 a = *(const float4*)src;
    float4 c = *(const float4*)(src + 4);
    bf16x8 v;
    v[0] = (bf16)a.x; v[1] = (bf16)a.y; v[2] = (bf16)a.z; v[3] = (bf16)a.w;
    v[4] = (bf16)c.x; v[5] = (bf16)c.y; v[6] = (bf16)c.z; v[7] = (bf16)c.w;
    *(bf16x8*)(x + (size_t)row * HSZ_ + col8) = v;
}

// ---------------------------------------------------------------------------
// GEMM v6 (R25): 256^2 8-phase port (T3+T4 full structure, m201 template).
// History: 128^2 ladder v1 80us -> +T1 (FETCH 69->17MB) -> +T2 (conflicts
// 9.4M->0) -> +T4 counted vmcnt = ~65us, MfmaUtil 15% -- the 2-phase 128^2
// structural ceiling (m233). v6: 256x256 tile, BK=64, 512 thr = 8 waves
// (2Mx4N), per-wave 128x64 out (acc[8][4]), LDS 128KB dbuf. 4 phases/K-tile
// = {k-chunk x m-half}: ds_read subtile || front-loaded glds16 prefetch
// (8 loads in phases 0-1 -> >=2 phases latency cover) -> s_barrier+
// sched_barrier(0) -> setprio(1)+16 MFMA+setprio(0) -> barrier. Tile
// boundary: vmcnt(0) (loads >=2 phases old) before the publish barrier.
// T1 bijective XCD swizzle + T2 both-sides XOR swizzle kept verbatim.
// MODE 4: fused QKV; MODE 2: bias+PReLU bf16; MODE 3: bias+residual f32.
template <int MODE>
__global__ __launch_bounds__(512, 2) void gemm_bt(const bf16* __restrict__ A,
                                                  const bf16* __restrict__ Bt,
                                                  const float* __restrict__ biasF,
                                                  const float* __restrict__ alphaF,
                                                  const bf16* __restrict__ extraB,
                                                  bf16* __restrict__ outB,
                                                  bf16* __restrict__ outB2,
                                                  bf16* __restrict__ outB3,
                                                  float* __restrict__ outF,
                                                  int Nn, int Kk) {
    __shared__ bf16 As[2][256][64];
    __shared__ bf16 Bs[2][256][64];

    // T1 bijective XCD swizzle (m204): all grids have nwg%8==0.
    int nwg = gridDim.x * gridDim.y;
    int bid = blockIdx.y * gridDim.x + blockIdx.x;
    int q = nwg >> 3;
    int ng = (bid & 7) * q + (bid >> 3);
    int bx = ng % gridDim.x, by = ng / gridDim.x;

    int n0 = bx * 256, m0 = by * 256;
    int t = threadIdx.x;
    int lane = t & 63, r = lane & 15, quad = lane >> 4;
    int wid = t >> 6;                 // 0..7
    int wr = wid >> 2, wc = wid & 3;  // 2M x 4N

    // staging: 512 threads cover 64 rows/pass x 8 chunks; passes {0,64,128,192}.
    // T2 both-sides: linear LDS dest chunk, global source chunk ^ (row&7).
    int sRow = t >> 3;                // 0..63
    int xr   = sRow & 7;              // shared by all 4 passes (64 apart)
    int sColL = (t & 7) * 8;
    int sColG = ((t & 7) ^ xr) * 8;
    const bf16* Ag = A  + (size_t)(m0 + sRow) * Kk + sColG;
    const bf16* Bg = Bt + (size_t)(n0 + sRow) * Kk + sColG;

#define GL_A(p_, off_, k0_) glds16(Ag + (size_t)(off_) * Kk + (k0_), &As[p_][sRow + (off_)][sColL])
#define GL_B(p_, off_, k0_) glds16(Bg + (size_t)(off_) * Kk + (k0_), &Bs[p_][sRow + (off_)][sColL])
#define PHASE_BAR() do { __builtin_amdgcn_s_barrier(); __builtin_amdgcn_sched_barrier(0); } while (0)

    f32x4 acc[8][4];
    #pragma unroll
    for (int mt = 0; mt < 8; mt++)
        #pragma unroll
        for (int nt = 0; nt < 4; nt++) acc[mt][nt] = (f32x4){0.f, 0.f, 0.f, 0.f};

    int xa = r & 7;   // read-side swizzle key (fragment row&7 == r&7)

    // prologue: stage tile 0 fully, drain, publish
    GL_A(0, 0, 0); GL_A(0, 64, 0); GL_A(0, 128, 0); GL_A(0, 192, 0);
    GL_B(0, 0, 0); GL_B(0, 64, 0); GL_B(0, 128, 0); GL_B(0, 192, 0);
    asm volatile("s_waitcnt vmcnt(0)" ::: "memory");
    __builtin_amdgcn_s_barrier();

    int ntiles = Kk >> 6;
    for (int tt = 0; tt < ntiles; tt++) {
        int p = tt & 1, pn = p ^ 1;
        bool pf = (tt + 1 < ntiles);
        int k1 = (tt + 1) << 6;
        bf16x8 af[4], bfr[4];
        int pc0 = ((0 + quad) ^ xa) * 8;   // kk=0
        int pc1 = ((4 + quad) ^ xa) * 8;   // kk=32

        // ---- phase 0: kk=0, m-half 0, B(kk=0); prefetch 4 of 8
        #pragma unroll
        for (int i = 0; i < 4; i++) {
            af[i]  = *(const bf16x8*)&As[p][wr * 128 + i * 16 + r][pc0];
            bfr[i] = *(const bf16x8*)&Bs[p][wc * 64 + i * 16 + r][pc0];
        }
        if (pf) { GL_A(pn, 0, k1); GL_A(pn, 64, k1); GL_B(pn, 0, k1); GL_B(pn, 64, k1); }
        PHASE_BAR();
        __builtin_amdgcn_s_setprio(1);
        #pragma unroll
        for (int mt = 0; mt < 4; mt++)
            #pragma unroll
            for (int nt = 0; nt < 4; nt++)
                acc[mt][nt] = __builtin_amdgcn_mfma_f32_16x16x32_bf16(af[mt], bfr[nt], acc[mt][nt], 0, 0, 0);
        __builtin_amdgcn_s_setprio(0);
        PHASE_BAR();

        // ---- phase 1: kk=0, m-half 1; prefetch remaining 4
        #pragma unroll
        for (int i = 0; i < 4; i++)
            af[i] = *(const bf16x8*)&As[p][wr * 128 + (i + 4) * 16 + r][pc0];
        if (pf) { GL_A(pn, 128, k1); GL_A(pn, 192, k1); GL_B(pn, 128, k1); GL_B(pn, 192, k1); }
        PHASE_BAR();
        __builtin_amdgcn_s_setprio(1);
        #pragma unroll
        for (int mt = 0; mt < 4; mt++)
            #pragma unroll
            for (int nt = 0; nt < 4; nt++)
                acc[mt + 4][nt] = __builtin_amdgcn_mfma_f32_16x16x32_bf16(af[mt], bfr[nt], acc[mt + 4][nt], 0, 0, 0);
        __builtin_amdgcn_s_setprio(0);
        PHASE_BAR();

        // ---- phase 2: kk=32, m-half 0, B(kk=32)
        #pragma unroll
        for (int i = 0; i < 4; i++) {
            af[i]  = *(const bf16x8*)&As[p][wr * 128 + i * 16 + r][pc1];
            bfr[i] = *(const bf16x8*)&Bs[p][wc * 64 + i * 16 + r][pc1];
        }
        PHASE_BAR();
        __builtin_amdgcn_s_setprio(1);
        #pragma unroll
        for (int mt = 0; mt < 4; mt++)
            #pragma unroll
            for (int nt = 0; nt < 4; nt++)
                acc[mt][nt] = __builtin_amdgcn_mfma_f32_16x16x32_bf16(af[mt], bfr[nt], acc[mt][nt], 0, 0, 0);
        __builtin_amdgcn_s_setprio(0);
        PHASE_BAR();

        // ---- phase 3: kk=32, m-half 1; boundary drain + publish
        #pragma unroll
        for (int i = 0; i < 4; i++)
            af[i] = *(const bf16x8*)&As[p][wr * 128 + (i + 4) * 16 + r][pc1];
        PHASE_BAR();
        __builtin_amdgcn_s_setprio(1);
        #pragma unroll
        for (int mt = 0; mt < 4; mt++)
            #pragma unroll
            for (int nt = 0; nt < 4; nt++)
                acc[mt + 4][nt] = __builtin_amdgcn_mfma_f32_16x16x32_bf16(af[mt], bfr[nt], acc[mt + 4][nt], 0, 0, 0);
        __builtin_amdgcn_s_setprio(0);
        asm volatile("s_waitcnt vmcnt(0)" ::: "memory");   // next tile landed (>=2-phase-old loads)
        PHASE_BAR();
    }
#undef GL_A
#undef GL_B
#undef PHASE_BAR

    #pragma unroll
    for (int mt = 0; mt < 8; mt++) {
        #pragma unroll
        for (int nt = 0; nt < 4; nt++) {
            #pragma unroll
            for (int i = 0; i < 4; i++) {
                int rg = m0 + wr * 128 + mt * 16 + quad * 4 + i;
                int cg = n0 + wc * 64 + nt * 16 + r;
                float v = acc[mt][nt][i];
                if (MODE == 2) {
                    v += biasF[cg];
                    float a = alphaF[cg];
                    v = v > 0.f ? v : a * v;
                    outB[(size_t)rg * Nn + cg] = (bf16)v;
                } else if (MODE == 3) {
                    v += biasF[cg] + (float)extraB[(size_t)rg * Nn + cg];
                    outF[(size_t)rg * Nn + cg] = v;
                } else {   // MODE 4: fused QKV
                    if (cg < 512) {
                        outB[(size_t)rg * HSZ_ + cg] = (bf16)v;
                    } else if (cg < 1024) {
                        outB2[(size_t)rg * HSZ_ + (cg - 512)] = (bf16)v;
                    } else {
                        int bb = rg >> 10, n = rg & 1023;
                        outB3[(size_t)(bb * HSZ_ + (cg - 1024)) * N_ + n] = (bf16)v;
                    }
                }
            }
        }
    }
}

// ---------------------------------------------------------------------------
// Fused MFMA attention v11 (proven ~65us). T14 single prefetch set of 8
// NAMED uint4 scalars; issue(it+1) right after the staging barrier so K/V
// latency flies under QK^T+softmax+PV. T5 setprio kept.
__global__ __launch_bounds__(256) void attn_fused(const bf16* __restrict__ Q,
                                                  const bf16* __restrict__ K,
                                                  const bf16* __restrict__ Vt,
                                                  const unsigned* __restrict__ adjw,
                                                  const bf16* __restrict__ xb,
                                                  float* __restrict__ tpre) {
    int blk = blockIdx.x;
    int gr = blk & 7;
    int qb = (blk >> 3) & 7;
    int gq = blk >> 6;
    int g = gq * 8 + gr;
    int b = g >> 2, h = g & 3;

    int tid = threadIdx.x;
    int w = tid >> 6, lane = tid & 63;
    int r = lane & 15, quad = lane >> 4;
    int n0 = qb * 128 + w * 32;      // this wave's 32 q-rows (2 m-tiles)

    __shared__ bf16 Ks[64][136];     // [key][dim], +8 pad -> 2-way (free)
    __shared__ bf16 Vs[128][72];     // [dim][key], +8 pad -> 2-way (free)
    __shared__ bf16 plds[4][32][68]; // per-wave P tile, padded

    int kRow = tid >> 4, kCol = (tid & 15) * 8;
    int vRow = tid >> 3, vCol = (tid & 7) * 8;
    const bf16* Kg = K + (size_t)(b * N_) * HSZ_ + h * 128 + (size_t)kRow * HSZ_ + kCol;
    const bf16* Vg = Vt + (size_t)(b * HSZ_ + h * 128 + vRow) * N_ + vCol;
    bf16* KsP = &Ks[kRow][kCol];
    bf16* VsP = &Vs[vRow][vCol];

    // single prefetch set: 8 named uint4 (rule #20: no arrays, no addr-taken)
    uint4 kp0, kp1, kp2, kp3, vp0, vp1, vp2, vp3;

#define ATTN_ISSUE(it_) do {                                                      \
        const bf16* kg_ = Kg + (size_t)(it_) * 64 * HSZ_;                         \
        const bf16* vg_ = Vg + (it_) * 64;                                        \
        kp0 = *(const uint4*)(kg_);                                               \
        kp1 = *(const uint4*)(kg_ + 16 * HSZ_);                                   \
        kp2 = *(const uint4*)(kg_ + 32 * HSZ_);                                   \
        kp3 = *(const uint4*)(kg_ + 48 * HSZ_);                                   \
        vp0 = *(const uint4*)(vg_);                                               \
        vp1 = *(const uint4*)(vg_ + 32 * N_);                                     \
        vp2 = *(const uint4*)(vg_ + 64 * N_);                                     \
        vp3 = *(const uint4*)(vg_ + 96 * N_);                                     \
    } while (0)

#define ATTN_COMMIT() do {                                                        \
        *(uint4*)(KsP)            = kp0;                                          \
        *(uint4*)(KsP + 16 * 136) = kp1;                                          \
        *(uint4*)(KsP + 32 * 136) = kp2;                                          \
        *(uint4*)(KsP + 48 * 136) = kp3;                                          \
        *(uint4*)(VsP)            = vp0;                                          \
        *(uint4*)(VsP + 32 * 72)  = vp1;                                          \
        *(uint4*)(VsP + 64 * 72)  = vp2;                                          \
        *(uint4*)(VsP + 96 * 72)  = vp3;                                          \
    } while (0)

    bf16x8 qf[2][4];
    #pragma unroll
    for (int mt = 0; mt < 2; mt++) {
        const bf16* qbase = Q + ((size_t)(b * N_ + n0 + mt * 16 + r)) * HSZ_ + h * 128;
        #pragma unroll
        for (int kc = 0; kc < 4; kc++) qf[mt][kc] = *(const bf16x8*)(qbase + kc * 32 + quad * 8);
    }

    f32x4 accv[2][8];
    #pragma unroll
    for (int mt = 0; mt < 2; mt++)
        #pragma unroll
        for (int dt = 0; dt < 8; dt++) accv[mt][dt] = (f32x4){0.f, 0.f, 0.f, 0.f};
    float tl[2][4] = {{0.f, 0.f, 0.f, 0.f}, {0.f, 0.f, 0.f, 0.f}};
    const float scale = 0.04419417382415922f;   // 1/sqrt(512)
    const float SHIFT = 12.0f;

    ATTN_ISSUE(0);
    for (int it = 0; it < 16; it++) {
        __syncthreads();               // all waves done reading Ks/Vs
        ATTN_COMMIT();                 // waits vmcnt for the prefetch set
        __syncthreads();               // staging visible
        if (it + 1 < 16) ATTN_ISSUE(it + 1);   // flies under compute

        // QK^T: 4 groups of 16 keys; K-fragment shared by both m-tiles
        f32x4 cg[2][4];
        #pragma unroll
        for (int mt = 0; mt < 2; mt++)
            #pragma unroll
            for (int gk = 0; gk < 4; gk++) cg[mt][gk] = (f32x4){0.f, 0.f, 0.f, 0.f};
        __builtin_amdgcn_s_setprio(1);
        #pragma unroll
        for (int gk = 0; gk < 4; gk++)
            #pragma unroll
            for (int kc = 0; kc < 4; kc++) {
                bf16x8 kf = *(const bf16x8*)&Ks[gk * 16 + r][kc * 32 + quad * 8];
                cg[0][gk] = __builtin_amdgcn_mfma_f32_16x16x32_bf16(qf[0][kc], kf, cg[0][gk], 0, 0, 0);
                cg[1][gk] = __builtin_amdgcn_mfma_f32_16x16x32_bf16(qf[1][kc], kf, cg[1][gk], 0, 0, 0);
            }
        __builtin_amdgcn_s_setprio(0);
        // mask + exp -> plds + tl
        #pragma unroll
        for (int mt = 0; mt < 2; mt++)
            #pragma unroll
            for (int i = 0; i < 4; i++) {
                int row_l = mt * 16 + quad * 4 + i;
                int row_g = n0 + row_l;
                const unsigned* aw = &adjw[((size_t)(b << 10) + row_g) * 32 + it * 2];
                unsigned wb0 = aw[0], wb1 = aw[1];
                float p0 = ((wb0 >> r) & 1u)        ? __expf(cg[mt][0][i] * scale - SHIFT) : 0.f;
                float p1 = ((wb0 >> (16 + r)) & 1u) ? __expf(cg[mt][1][i] * scale - SHIFT) : 0.f;
                float p2 = ((wb1 >> r) & 1u)        ? __expf(cg[mt][2][i] * scale - SHIFT) : 0.f;
                float p3 = ((wb1 >> (16 + r)) & 1u) ? __expf(cg[mt][3][i] * scale - SHIFT) : 0.f;
                tl[mt][i] += p0 + p1 + p2 + p3;
                plds[w][row_l][r]      = (bf16)p0;
                plds[w][row_l][16 + r] = (bf16)p1;
                plds[w][row_l][32 + r] = (bf16)p2;
                plds[w][row_l][48 + r] = (bf16)p3;
            }
        // no barrier: plds[w] is wave-private; same-wave DS ordering suffices

        // PV: P (A-op, 64 keys in 2 k-chunks) x Vs; V-fragments shared
        bf16x8 pf00 = *(const bf16x8*)&plds[w][r][quad * 8];
        bf16x8 pf01 = *(const bf16x8*)&plds[w][r][32 + quad * 8];
        bf16x8 pf10 = *(const bf16x8*)&plds[w][16 + r][quad * 8];
        bf16x8 pf11 = *(const bf16x8*)&plds[w][16 + r][32 + quad * 8];
        __builtin_amdgcn_s_setprio(1);
        #pragma unroll
        for (int dt = 0; dt < 8; dt++) {
            bf16x8 v0 = *(const bf16x8*)&Vs[dt * 16 + r][quad * 8];
            bf16x8 v1 = *(const bf16x8*)&Vs[dt * 16 + r][32 + quad * 8];
            accv[0][dt] = __builtin_amdgcn_mfma_f32_16x16x32_bf16(pf00, v0, accv[0][dt], 0, 0, 0);
            accv[0][dt] = __builtin_amdgcn_mfma_f32_16x16x32_bf16(pf01, v1, accv[0][dt], 0, 0, 0);
            accv[1][dt] = __builtin_amdgcn_mfma_f32_16x16x32_bf16(pf10, v0, accv[1][dt], 0, 0, 0);
            accv[1][dt] = __builtin_amdgcn_mfma_f32_16x16x32_bf16(pf11, v1, accv[1][dt], 0, 0, 0);
        }
        __builtin_amdgcn_s_setprio(0);
    }
#undef ATTN_ISSUE
#undef ATTN_COMMIT

    // per-wave epilogue
    #pragma unroll
    for (int mt = 0; mt < 2; mt++)
        #pragma unroll
        for (int i = 0; i < 4; i++) {
            float l = tl[mt][i];
            #pragma unroll
            for (int d = 1; d < 16; d <<= 1) l += __shfl_xor(l, d, 64);
            float inv_l = 1.0f / fmaxf(l, 1e-30f);
            #pragma unroll
            for (int dt = 0; dt < 8; dt++) {
                int row = n0 + mt * 16 + quad * 4 + i;
                int col = h * 128 + dt * 16 + r;
                size_t idx = ((size_t)(b * N_ + row)) * HSZ_ + col;
                tpre[idx] = accv[mt][dt][i] * inv_l + (float)xb[idx];
            }
        }
}

// ---------------------------------------------------------------------------
// wave-per-row layernorm, 4 rows/block. OUT=0: bf16 to outB (intermediate).
// OUT=1: final lnorm2 of j=1 writes f32 directly to d_out (nodes + glob
// duplicate at n==E_); blocks >= 4096 fill node_mask with 1.0f.
template <int OUT>
__global__ __launch_bounds__(256) void lnorm_k(const float* __restrict__ in,
                                               const float* __restrict__ sc,
                                               const float* __restrict__ bi,
                                               bf16* __restrict__ outB,
                                               float* __restrict__ outF) {
    if (OUT == 1 && blockIdx.x >= 4096) {
        int idx = (blockIdx.x - 4096) * 1024 + threadIdx.x * 4;
        float4 one = {1.f, 1.f, 1.f, 1.f};
        *(float4*)&outF[(size_t)B_ * HSZ_ + (size_t)B_ * N_ * HSZ_ + idx] = one;
        return;
    }
    int row = blockIdx.x * 4 + (threadIdx.x >> 6);
    int lane = threadIdx.x & 63;
    const float* rp = in + (size_t)row * HSZ_;
    float4 a = *(const float4*)(rp + lane * 4);
    float4 b = *(const float4*)(rp + 256 + lane * 4);
    float sum = a.x + a.y + a.z + a.w + b.x + b.y + b.z + b.w;
    float sq  = a.x*a.x + a.y*a.y + a.z*a.z + a.w*a.w
              + b.x*b.x + b.y*b.y + b.z*b.z + b.w*b.w;
    #pragma unroll
    for (int d = 1; d < 64; d <<= 1) {
        sum += __shfl_xor(sum, d, 64);
        sq  += __shfl_xor(sq,  d, 64);
    }
    float mu = sum * (1.0f / HSZ_);
    float varv = fmaxf(sq * (1.0f / HSZ_) - mu * mu, 0.f);
    float rs = rsqrtf(varv + 1e-5f);
    int c0 = lane * 4;
    float va[4] = {a.x, a.y, a.z, a.w}, vb[4] = {b.x, b.y, b.z, b.w};
    if (OUT == 0) {
        bf16* op = outB + (size_t)row * HSZ_;
        #pragma unroll
        for (int k = 0; k < 4; k++) {
            op[c0 + k]       = (bf16)(((va[k] - mu) * rs) * sc[c0 + k] + bi[c0 + k]);
            op[c0 + 256 + k] = (bf16)(((vb[k] - mu) * rs) * sc[c0 + 256 + k] + bi[c0 + 256 + k]);
        }
    } else {
        float4 o1, o2;
        o1.x = ((va[0] - mu) * rs) * sc[c0 + 0] + bi[c0 + 0];
        o1.y = ((va[1] - mu) * rs) * sc[c0 + 1] + bi[c0 + 1];
        o1.z = ((va[2] - mu) * rs) * sc[c0 + 2] + bi[c0 + 2];
        o1.w = ((va[3] - mu) * rs) * sc[c0 + 3] + bi[c0 + 3];
        o2.x = ((vb[0] - mu) * rs) * sc[c0 + 256] + bi[c0 + 256];
        o2.y = ((vb[1] - mu) * rs) * sc[c0 + 257] + bi[c0 + 257];
        o2.z = ((vb[2] - mu) * rs) * sc[c0 + 258] + bi[c0 + 258];
        o2.w = ((vb[3] - mu) * rs) * sc[c0 + 259] + bi[c0 + 259];
        float* nodes = outF + (size_t)B_ * HSZ_;
        *(float4*)&nodes[(size_t)row * HSZ_ + c0]       = o1;
        *(float4*)&nodes[(size_t)row * HSZ_ + c0 + 256] = o2;
        int bb = row >> 10, n = row & 1023;
        if (n == E_) {
            *(float4*)&outF[(size_t)bb * HSZ_ + c0]       = o1;
            *(float4*)&outF[(size_t)bb * HSZ_ + c0 + 256] = o2;
        }
    }
}

// ---------------------------------------------------------------------------
extern "C" void kernel_launch(void* const* d_in, const int* in_sizes, int n_in,
                              void* d_out, int out_size, void* d_ws, size_t ws_size,
                              hipStream_t stream) {
    const float* ents = (const float*)d_in[0];
    const int*   rels = (const int*)d_in[1];
    const int*   adj  = (const int*)d_in[2];
    const float* renc = (const float*)d_in[3];
    const float* Wq   = (const float*)d_in[4];
    const float* Wk   = (const float*)d_in[5];
    const float* Wv   = (const float*)d_in[6];
    const float* l1w  = (const float*)d_in[7];
    const float* l1b  = (const float*)d_in[8];
    const float* l2w  = (const float*)d_in[9];
    const float* l2b  = (const float*)d_in[10];
    const float* ln1s = (const float*)d_in[11];
    const float* ln1b = (const float*)d_in[12];
    const float* ln2s = (const float*)d_in[13];
    const float* ln2b = (const float*)d_in[14];
    const float* pa   = (const float*)d_in[15];

    char* ws = (char*)d_ws;
    size_t o = 0;
    auto alloc = [&](size_t bytes) { void* p = ws + o; o += bytes; return p; };
    bf16*     WqkvT  = (bf16*)alloc(3145728);   // per j: 1536 rows x 512 (Wq|Wk|Wv)^T
    bf16*     L1T    = (bf16*)alloc(4194304);
    bf16*     L2T    = (bf16*)alloc(4194304);
    unsigned* adjw   = (unsigned*)alloc(2097152);
    bf16*     xb     = (bf16*)alloc(16777216);
    bf16*     Qb     = (bf16*)alloc(16777216);
    bf16*     Kb     = (bf16*)alloc(16777216);
    bf16*     Vt     = (bf16*)alloc(16777216);
    bf16*     tb     = (bf16*)alloc(16777216);
    bf16*     hb     = (bf16*)alloc(67108864);
    float*    f32buf = (float*)alloc(33554432);
    if (o > ws_size) return;

    transpose_all<<<5632, 256, 0, stream>>>(Wq, Wk, Wv, l1w, l2w, WqkvT, L1T, L2T);
    pack_adj<<<65536, 256, 0, stream>>>(adj, adjw);
    build_x<<<4096, 256, 0, stream>>>(ents, rels, renc, xb);

    for (int j = 0; j < 2; j++) {
        gemm_bt<4><<<dim3(6, 64), 512, 0, stream>>>(xb, WqkvT + j * 786432, nullptr, nullptr, nullptr,
                                                    Qb, Kb, Vt, nullptr, 1536, 512);
        attn_fused<<<512, 256, 0, stream>>>(Qb, Kb, Vt, adjw, xb, f32buf);
        lnorm_k<0><<<4096, 256, 0, stream>>>(f32buf, ln1s + j * 512, ln1b + j * 512, tb, nullptr);
        gemm_bt<2><<<dim3(8, 64), 512, 0, stream>>>(tb, L1T + j * 1048576, l1b + j * 2048, pa + j * 2048,
                                                    nullptr, hb, nullptr, nullptr, nullptr, 2048, 512);
        gemm_bt<3><<<dim3(2, 64), 512, 0, stream>>>(hb, L2T + j * 1048576, l2b + j * 512, nullptr,
                                                    tb, nullptr, nullptr, nullptr, f32buf, 512, 2048);
        if (j == 0)
            lnorm_k<0><<<4096, 256, 0, stream>>>(f32buf, ln2s, ln2b, xb, nullptr);
        else
            lnorm_k<1><<<4112, 256, 0, stream>>>(f32buf, ln2s + 512, ln2b + 512, nullptr, (float*)d_out);
    }
}

// Round 13
// 638.818 us; speedup vs baseline: 1.1040x; 1.1040x over previous
//
#include <hip/hip_runtime.h>
#include <hip/hip_bf16.h>

typedef __bf16 bf16;
typedef __attribute__((ext_vector_type(8))) bf16 bf16x8;
typedef __attribute__((ext_vector_type(4))) float f32x4;

constexpr int B_   = 16;
constexpr int E_   = 400;
constexpr int R_   = 624;
constexpr int N_   = 1024;
constexpr int HSZ_ = 512;
constexpr int DFF_ = 2048;
constexpr int M_   = B_ * N_;

// global -> LDS direct DMA, 16B per lane (wave-uniform base + lane*16 dest).
__device__ __forceinline__ void glds16(const void* g, void* l) {
    __builtin_amdgcn_global_load_lds((const __attribute__((address_space(1))) void*)g,
                                     (__attribute__((address_space(3))) void*)l,
                                     16, 0, 0);
}

// ---------------------------------------------------------------------------
// All 10 weight transposes merged into ONE launch. Block-range dispatch.
__global__ __launch_bounds__(256) void transpose_all(const float* __restrict__ Wq,
                                                     const float* __restrict__ Wk,
                                                     const float* __restrict__ Wv,
                                                     const float* __restrict__ l1w,
                                                     const float* __restrict__ l2w,
                                                     bf16* __restrict__ WqkvT,
                                                     bf16* __restrict__ L1T,
                                                     bf16* __restrict__ L2T) {
    __shared__ float tile[32][33];
    int id = blockIdx.x;
    const float* in;
    bf16* out;
    int rows, cols, bx, by;
    if (id < 1536) {
        int grp = id >> 8;            // 0..5 = (j, {q,k,v})
        int loc = id & 255;
        bx = loc & 15; by = loc >> 4;
        rows = 512; cols = 512;
        int j = grp / 3, wsel = grp % 3;
        const float* W = (wsel == 0) ? Wq : (wsel == 1) ? Wk : Wv;
        in  = W + j * 262144;
        out = WqkvT + j * 786432 + wsel * 262144;
    } else if (id < 3584) {
        int loc = id - 1536;
        int j = loc >= 1024; loc &= 1023;
        bx = loc & 63; by = loc >> 6;
        rows = 512; cols = 2048;
        in  = l1w + j * 1048576;
        out = L1T + j * 1048576;
    } else {
        int loc = id - 3584;
        int j = loc >= 1024; loc &= 1023;
        bx = loc & 15; by = loc >> 4;
        rows = 2048; cols = 512;
        in  = l2w + j * 1048576;
        out = L2T + j * 1048576;
    }
    int tx = threadIdx.x & 31, ty = threadIdx.x >> 5;   // 32 x 8
    int c0 = bx * 32, r0 = by * 32;
    #pragma unroll
    for (int i = 0; i < 32; i += 8)
        tile[ty + i][tx] = in[(size_t)(r0 + ty + i) * cols + (c0 + tx)];
    __syncthreads();
    #pragma unroll
    for (int i = 0; i < 32; i += 8)
        out[(size_t)(c0 + ty + i) * rows + (r0 + tx)] = (bf16)tile[tx][ty + i];
}

// ---------------------------------------------------------------------------
__global__ __launch_bounds__(256) void pack_adj(const int* __restrict__ adj,
                                                unsigned* __restrict__ adjw) {
    int gid  = blockIdx.x * 4 + (threadIdx.x >> 6);
    int lane = threadIdx.x & 63;
    int w64  = gid & 15;
    int bn   = gid >> 4;
    int v = adj[(size_t)bn * N_ + w64 * 64 + lane];
    unsigned long long mask = __ballot(v != 0);
    if (lane == 0)  adjw[bn * 32 + w64 * 2]     = (unsigned)mask;
    if (lane == 32) adjw[bn * 32 + w64 * 2 + 1] = (unsigned)(mask >> 32);
}

// ---------------------------------------------------------------------------
__global__ __launch_bounds__(256) void build_x(const float* __restrict__ ents,
                                               const int* __restrict__ rels,
                                               const float* __restrict__ renc,
                                               bf16* __restrict__ x) {
    int idx  = blockIdx.x * 256 + threadIdx.x;
    int col8 = (idx & 63) * 8;
    int row  = idx >> 6;
    int b = row >> 10, n = row & 1023;
    const float* src;
    if (n < E_) src = ents + ((size_t)(b * E_ + n)) * HSZ_ + col8;
    else {
        int rt = rels[b * R_ + (n - E_)];
        src = renc + (size_t)rt * HSZ_ + col8;
    }
    float4 a = *(const float4*)src;
    float4 c = *(const float4*)(src + 4);
    bf16x8 v;
    v[0] = (bf16)a.x; v[1] = (bf16)a.y; v[2] = (bf16)a.z; v[3] = (bf16)a.w;
    v[4] = (bf16)c.x; v[5] = (bf16)c.y; v[6] = (bf16)c.z; v[7] = (bf16)c.w;
    *(bf16x8*)(x + (size_t)row * HSZ_ + col8) = v;
}

// ---------------------------------------------------------------------------
// GEMM v5 (PROVEN best, R10/R11). 128x128 tile, BK=64, 4 waves, 256 thr.
// T1 bijective XCD swizzle (FETCH 69->17MB) + T2 both-sides XOR swizzle
// (conflicts 9.4M->0) + T4 counted-vmcnt dbuf (raw s_barrier, no vmcnt(0)
// drain in loop; sched_barrier(0) pins per rule #18).
// R26 ERRATA: the 256^2 8-phase port (R25) REGRESSED 65->95us: at these
// skinny shapes FF2's grid is 128 blocks (half the GPU idle), 128KB LDS ->
// 1 blk/CU kills the m114 implicit wave-overlap, K=8 tiles can't amortize
// the deeper pipeline. 128^2/2-blk is the empirical structure optimum here.
// MODE 4: fused QKV — cols 0-511 -> outB (Qb), 512-1023 -> outB2 (Kb),
// 1024-1535 -> outB3 (Vt transposed). Branch is block-uniform.
template <int MODE>
__global__ __launch_bounds__(256) void gemm_bt(const bf16* __restrict__ A,
                                               const bf16* __restrict__ Bt,
                                               const float* __restrict__ biasF,
                                               const float* __restrict__ alphaF,
                                               const bf16* __restrict__ extraB,
                                               bf16* __restrict__ outB,
                                               bf16* __restrict__ outB2,
                                               bf16* __restrict__ outB3,
                                               float* __restrict__ outF,
                                               int Nn, int Kk) {
    __shared__ bf16 As[2][128][64];
    __shared__ bf16 Bs[2][128][64];

    int nwg = gridDim.x * gridDim.y;
    int bid = blockIdx.y * gridDim.x + blockIdx.x;   // dispatch order, x fastest
    int q = nwg >> 3;
    int ng = (bid & 7) * q + (bid >> 3);
    int bx = ng % gridDim.x, by = ng / gridDim.x;

    int n0 = bx * 128, m0 = by * 128;
    int t = threadIdx.x;
    int lane = t & 63, r = lane & 15, quad = lane >> 4;
    int w = t >> 6;
    int wm = w >> 1, wn = w & 1;

    int sRow = t >> 3;
    int xr   = sRow & 7;
    int sColL = (t & 7) * 8;                  // linear LDS chunk col
    int sColG = ((t & 7) ^ xr) * 8;           // pre-swizzled global chunk col
    const bf16* Ag = A  + (size_t)(m0 + sRow) * Kk + sColG;
    const bf16* Bg = Bt + (size_t)(n0 + sRow) * Kk + sColG;

#define G_STAGE(p_, k0_) do {                                          \
        glds16(Ag + (k0_),           &As[p_][sRow     ][sColL]);       \
        glds16(Ag + 32 * Kk + (k0_), &As[p_][sRow + 32][sColL]);       \
        glds16(Ag + 64 * Kk + (k0_), &As[p_][sRow + 64][sColL]);       \
        glds16(Ag + 96 * Kk + (k0_), &As[p_][sRow + 96][sColL]);       \
        glds16(Bg + (k0_),           &Bs[p_][sRow     ][sColL]);       \
        glds16(Bg + 32 * Kk + (k0_), &Bs[p_][sRow + 32][sColL]);       \
        glds16(Bg + 64 * Kk + (k0_), &Bs[p_][sRow + 64][sColL]);       \
        glds16(Bg + 96 * Kk + (k0_), &Bs[p_][sRow + 96][sColL]);       \
    } while (0)

    f32x4 acc[4][4];
    #pragma unroll
    for (int mt = 0; mt < 4; mt++)
        #pragma unroll
        for (int nt = 0; nt < 4; nt++) acc[mt][nt] = (f32x4){0.f, 0.f, 0.f, 0.f};

    int xa = r & 7;   // read-side swizzle key: fragment rows -> row&7 = r&7

    G_STAGE(0, 0);
    int ntiles = Kk >> 6;
    for (int tt = 0; tt < ntiles; tt++) {
        int p = tt & 1;
        if (tt + 1 < ntiles) {
            G_STAGE(p ^ 1, (tt + 1) * 64);              // 8 new loads in flight
            asm volatile("s_waitcnt vmcnt(8)" ::: "memory");  // tile t landed
        } else {
            asm volatile("s_waitcnt vmcnt(0)" ::: "memory");  // epilogue drain
        }
        __builtin_amdgcn_s_barrier();                   // raw: no vmcnt(0)
        __builtin_amdgcn_sched_barrier(0);
        #pragma unroll
        for (int kk = 0; kk < 64; kk += 32) {
            int pc = (((kk >> 3) + quad) ^ xa) * 8;
            bf16x8 af[4], bfr[4];
            #pragma unroll
            for (int mt = 0; mt < 4; mt++)
                af[mt] = *(const bf16x8*)&As[p][wm * 64 + mt * 16 + r][pc];
            #pragma unroll
            for (int nt = 0; nt < 4; nt++)
                bfr[nt] = *(const bf16x8*)&Bs[p][wn * 64 + nt * 16 + r][pc];
            #pragma unroll
            for (int mt = 0; mt < 4; mt++)
                #pragma unroll
                for (int nt = 0; nt < 4; nt++)
                    acc[mt][nt] = __builtin_amdgcn_mfma_f32_16x16x32_bf16(af[mt], bfr[nt], acc[mt][nt], 0, 0, 0);
        }
        __builtin_amdgcn_s_barrier();                   // buf[p] reads done
        __builtin_amdgcn_sched_barrier(0);              // pin: no stage hoist
    }
#undef G_STAGE

    #pragma unroll
    for (int mt = 0; mt < 4; mt++) {
        #pragma unroll
        for (int nt = 0; nt < 4; nt++) {
            #pragma unroll
            for (int i = 0; i < 4; i++) {
                int rg = m0 + wm * 64 + mt * 16 + quad * 4 + i;
                int cg = n0 + wn * 64 + nt * 16 + r;
                float v = acc[mt][nt][i];
                if (MODE == 0) {
                    outB[(size_t)rg * Nn + cg] = (bf16)v;
                } else if (MODE == 1) {
                    int bb = rg >> 10, n = rg & 1023;
                    outB[(size_t)(bb * HSZ_ + cg) * N_ + n] = (bf16)v;
                } else if (MODE == 2) {
                    v += biasF[cg];
                    float a = alphaF[cg];
                    v = v > 0.f ? v : a * v;
                    outB[(size_t)rg * Nn + cg] = (bf16)v;
                } else if (MODE == 3) {
                    v += biasF[cg] + (float)extraB[(size_t)rg * Nn + cg];
                    outF[(size_t)rg * Nn + cg] = v;
                } else {   // MODE 4: fused QKV
                    if (cg < 512) {
                        outB[(size_t)rg * HSZ_ + cg] = (bf16)v;
                    } else if (cg < 1024) {
                        outB2[(size_t)rg * HSZ_ + (cg - 512)] = (bf16)v;
                    } else {
                        int bb = rg >> 10, n = rg & 1023;
                        outB3[(size_t)(bb * HSZ_ + (cg - 1024)) * N_ + n] = (bf16)v;
                    }
                }
            }
        }
    }
}

// ---------------------------------------------------------------------------
// Fused MFMA attention v11 (proven ~65us). T14 single prefetch set of 8
// NAMED uint4 scalars; issue(it+1) right after the staging barrier so K/V
// latency flies under QK^T+softmax+PV. T5 setprio kept.
__global__ __launch_bounds__(256) void attn_fused(const bf16* __restrict__ Q,
                                                  const bf16* __restrict__ K,
                                                  const bf16* __restrict__ Vt,
                                                  const unsigned* __restrict__ adjw,
                                                  const bf16* __restrict__ xb,
                                                  float* __restrict__ tpre) {
    int blk = blockIdx.x;
    int gr = blk & 7;
    int qb = (blk >> 3) & 7;
    int gq = blk >> 6;
    int g = gq * 8 + gr;
    int b = g >> 2, h = g & 3;

    int tid = threadIdx.x;
    int w = tid >> 6, lane = tid & 63;
    int r = lane & 15, quad = lane >> 4;
    int n0 = qb * 128 + w * 32;      // this wave's 32 q-rows (2 m-tiles)

    __shared__ bf16 Ks[64][136];     // [key][dim], +8 pad -> 2-way (free)
    __shared__ bf16 Vs[128][72];     // [dim][key], +8 pad -> 2-way (free)
    __shared__ bf16 plds[4][32][68]; // per-wave P tile, padded

    int kRow = tid >> 4, kCol = (tid & 15) * 8;
    int vRow = tid >> 3, vCol = (tid & 7) * 8;
    const bf16* Kg = K + (size_t)(b * N_) * HSZ_ + h * 128 + (size_t)kRow * HSZ_ + kCol;
    const bf16* Vg = Vt + (size_t)(b * HSZ_ + h * 128 + vRow) * N_ + vCol;
    bf16* KsP = &Ks[kRow][kCol];
    bf16* VsP = &Vs[vRow][vCol];

    // single prefetch set: 8 named uint4 (rule #20: no arrays, no addr-taken)
    uint4 kp0, kp1, kp2, kp3, vp0, vp1, vp2, vp3;

#define ATTN_ISSUE(it_) do {                                                      \
        const bf16* kg_ = Kg + (size_t)(it_) * 64 * HSZ_;                         \
        const bf16* vg_ = Vg + (it_) * 64;                                        \
        kp0 = *(const uint4*)(kg_);                                               \
        kp1 = *(const uint4*)(kg_ + 16 * HSZ_);                                   \
        kp2 = *(const uint4*)(kg_ + 32 * HSZ_);                                   \
        kp3 = *(const uint4*)(kg_ + 48 * HSZ_);                                   \
        vp0 = *(const uint4*)(vg_);                                               \
        vp1 = *(const uint4*)(vg_ + 32 * N_);                                     \
        vp2 = *(const uint4*)(vg_ + 64 * N_);                                     \
        vp3 = *(const uint4*)(vg_ + 96 * N_);                                     \
    } while (0)

#define ATTN_COMMIT() do {                                                        \
        *(uint4*)(KsP)            = kp0;                                          \
        *(uint4*)(KsP + 16 * 136) = kp1;                                          \
        *(uint4*)(KsP + 32 * 136) = kp2;                                          \
        *(uint4*)(KsP + 48 * 136) = kp3;                                          \
        *(uint4*)(VsP)            = vp0;                                          \
        *(uint4*)(VsP + 32 * 72)  = vp1;                                          \
        *(uint4*)(VsP + 64 * 72)  = vp2;                                          \
        *(uint4*)(VsP + 96 * 72)  = vp3;                                          \
    } while (0)

    bf16x8 qf[2][4];
    #pragma unroll
    for (int mt = 0; mt < 2; mt++) {
        const bf16* qbase = Q + ((size_t)(b * N_ + n0 + mt * 16 + r)) * HSZ_ + h * 128;
        #pragma unroll
        for (int kc = 0; kc < 4; kc++) qf[mt][kc] = *(const bf16x8*)(qbase + kc * 32 + quad * 8);
    }

    f32x4 accv[2][8];
    #pragma unroll
    for (int mt = 0; mt < 2; mt++)
        #pragma unroll
        for (int dt = 0; dt < 8; dt++) accv[mt][dt] = (f32x4){0.f, 0.f, 0.f, 0.f};
    float tl[2][4] = {{0.f, 0.f, 0.f, 0.f}, {0.f, 0.f, 0.f, 0.f}};
    const float scale = 0.04419417382415922f;   // 1/sqrt(512)
    const float SHIFT = 12.0f;

    ATTN_ISSUE(0);
    for (int it = 0; it < 16; it++) {
        __syncthreads();               // all waves done reading Ks/Vs
        ATTN_COMMIT();                 // waits vmcnt for the prefetch set
        __syncthreads();               // staging visible
        if (it + 1 < 16) ATTN_ISSUE(it + 1);   // flies under compute

        // QK^T: 4 groups of 16 keys; K-fragment shared by both m-tiles
        f32x4 cg[2][4];
        #pragma unroll
        for (int mt = 0; mt < 2; mt++)
            #pragma unroll
            for (int gk = 0; gk < 4; gk++) cg[mt][gk] = (f32x4){0.f, 0.f, 0.f, 0.f};
        __builtin_amdgcn_s_setprio(1);
        #pragma unroll
        for (int gk = 0; gk < 4; gk++)
            #pragma unroll
            for (int kc = 0; kc < 4; kc++) {
                bf16x8 kf = *(const bf16x8*)&Ks[gk * 16 + r][kc * 32 + quad * 8];
                cg[0][gk] = __builtin_amdgcn_mfma_f32_16x16x32_bf16(qf[0][kc], kf, cg[0][gk], 0, 0, 0);
                cg[1][gk] = __builtin_amdgcn_mfma_f32_16x16x32_bf16(qf[1][kc], kf, cg[1][gk], 0, 0, 0);
            }
        __builtin_amdgcn_s_setprio(0);
        // mask + exp -> plds + tl
        #pragma unroll
        for (int mt = 0; mt < 2; mt++)
            #pragma unroll
            for (int i = 0; i < 4; i++) {
                int row_l = mt * 16 + quad * 4 + i;
                int row_g = n0 + row_l;
                const unsigned* aw = &adjw[((size_t)(b << 10) + row_g) * 32 + it * 2];
                unsigned wb0 = aw[0], wb1 = aw[1];
                float p0 = ((wb0 >> r) & 1u)        ? __expf(cg[mt][0][i] * scale - SHIFT) : 0.f;
                float p1 = ((wb0 >> (16 + r)) & 1u) ? __expf(cg[mt][1][i] * scale - SHIFT) : 0.f;
                float p2 = ((wb1 >> r) & 1u)        ? __expf(cg[mt][2][i] * scale - SHIFT) : 0.f;
                float p3 = ((wb1 >> (16 + r)) & 1u) ? __expf(cg[mt][3][i] * scale - SHIFT) : 0.f;
                tl[mt][i] += p0 + p1 + p2 + p3;
                plds[w][row_l][r]      = (bf16)p0;
                plds[w][row_l][16 + r] = (bf16)p1;
                plds[w][row_l][32 + r] = (bf16)p2;
                plds[w][row_l][48 + r] = (bf16)p3;
            }
        // no barrier: plds[w] is wave-private; same-wave DS ordering suffices

        // PV: P (A-op, 64 keys in 2 k-chunks) x Vs; V-fragments shared
        bf16x8 pf00 = *(const bf16x8*)&plds[w][r][quad * 8];
        bf16x8 pf01 = *(const bf16x8*)&plds[w][r][32 + quad * 8];
        bf16x8 pf10 = *(const bf16x8*)&plds[w][16 + r][quad * 8];
        bf16x8 pf11 = *(const bf16x8*)&plds[w][16 + r][32 + quad * 8];
        __builtin_amdgcn_s_setprio(1);
        #pragma unroll
        for (int dt = 0; dt < 8; dt++) {
            bf16x8 v0 = *(const bf16x8*)&Vs[dt * 16 + r][quad * 8];
            bf16x8 v1 = *(const bf16x8*)&Vs[dt * 16 + r][32 + quad * 8];
            accv[0][dt] = __builtin_amdgcn_mfma_f32_16x16x32_bf16(pf00, v0, accv[0][dt], 0, 0, 0);
            accv[0][dt] = __builtin_amdgcn_mfma_f32_16x16x32_bf16(pf01, v1, accv[0][dt], 0, 0, 0);
            accv[1][dt] = __builtin_amdgcn_mfma_f32_16x16x32_bf16(pf10, v0, accv[1][dt], 0, 0, 0);
            accv[1][dt] = __builtin_amdgcn_mfma_f32_16x16x32_bf16(pf11, v1, accv[1][dt], 0, 0, 0);
        }
        __builtin_amdgcn_s_setprio(0);
    }
#undef ATTN_ISSUE
#undef ATTN_COMMIT

    // per-wave epilogue
    #pragma unroll
    for (int mt = 0; mt < 2; mt++)
        #pragma unroll
        for (int i = 0; i < 4; i++) {
            float l = tl[mt][i];
            #pragma unroll
            for (int d = 1; d < 16; d <<= 1) l += __shfl_xor(l, d, 64);
            float inv_l = 1.0f / fmaxf(l, 1e-30f);
            #pragma unroll
            for (int dt = 0; dt < 8; dt++) {
                int row = n0 + mt * 16 + quad * 4 + i;
                int col = h * 128 + dt * 16 + r;
                size_t idx = ((size_t)(b * N_ + row)) * HSZ_ + col;
                tpre[idx] = accv[mt][dt][i] * inv_l + (float)xb[idx];
            }
        }
}

// ---------------------------------------------------------------------------
// wave-per-row layernorm, 4 rows/block. OUT=0: bf16 to outB (intermediate).
// OUT=1: final lnorm2 of j=1 writes f32 directly to d_out (nodes + glob
// duplicate at n==E_); blocks >= 4096 fill node_mask with 1.0f.
template <int OUT>
__global__ __launch_bounds__(256) void lnorm_k(const float* __restrict__ in,
                                               const float* __restrict__ sc,
                                               const float* __restrict__ bi,
                                               bf16* __restrict__ outB,
                                               float* __restrict__ outF) {
    if (OUT == 1 && blockIdx.x >= 4096) {
        int idx = (blockIdx.x - 4096) * 1024 + threadIdx.x * 4;
        float4 one = {1.f, 1.f, 1.f, 1.f};
        *(float4*)&outF[(size_t)B_ * HSZ_ + (size_t)B_ * N_ * HSZ_ + idx] = one;
        return;
    }
    int row = blockIdx.x * 4 + (threadIdx.x >> 6);
    int lane = threadIdx.x & 63;
    const float* rp = in + (size_t)row * HSZ_;
    float4 a = *(const float4*)(rp + lane * 4);
    float4 b = *(const float4*)(rp + 256 + lane * 4);
    float sum = a.x + a.y + a.z + a.w + b.x + b.y + b.z + b.w;
    float sq  = a.x*a.x + a.y*a.y + a.z*a.z + a.w*a.w
              + b.x*b.x + b.y*b.y + b.z*b.z + b.w*b.w;
    #pragma unroll
    for (int d = 1; d < 64; d <<= 1) {
        sum += __shfl_xor(sum, d, 64);
        sq  += __shfl_xor(sq,  d, 64);
    }
    float mu = sum * (1.0f / HSZ_);
    float varv = fmaxf(sq * (1.0f / HSZ_) - mu * mu, 0.f);
    float rs = rsqrtf(varv + 1e-5f);
    int c0 = lane * 4;
    float va[4] = {a.x, a.y, a.z, a.w}, vb[4] = {b.x, b.y, b.z, b.w};
    if (OUT == 0) {
        bf16* op = outB + (size_t)row * HSZ_;
        #pragma unroll
        for (int k = 0; k < 4; k++) {
            op[c0 + k]       = (bf16)(((va[k] - mu) * rs) * sc[c0 + k] + bi[c0 + k]);
            op[c0 + 256 + k] = (bf16)(((vb[k] - mu) * rs) * sc[c0 + 256 + k] + bi[c0 + 256 + k]);
        }
    } else {
        float4 o1, o2;
        o1.x = ((va[0] - mu) * rs) * sc[c0 + 0] + bi[c0 + 0];
        o1.y = ((va[1] - mu) * rs) * sc[c0 + 1] + bi[c0 + 1];
        o1.z = ((va[2] - mu) * rs) * sc[c0 + 2] + bi[c0 + 2];
        o1.w = ((va[3] - mu) * rs) * sc[c0 + 3] + bi[c0 + 3];
        o2.x = ((vb[0] - mu) * rs) * sc[c0 + 256] + bi[c0 + 256];
        o2.y = ((vb[1] - mu) * rs) * sc[c0 + 257] + bi[c0 + 257];
        o2.z = ((vb[2] - mu) * rs) * sc[c0 + 258] + bi[c0 + 258];
        o2.w = ((vb[3] - mu) * rs) * sc[c0 + 259] + bi[c0 + 259];
        float* nodes = outF + (size_t)B_ * HSZ_;
        *(float4*)&nodes[(size_t)row * HSZ_ + c0]       = o1;
        *(float4*)&nodes[(size_t)row * HSZ_ + c0 + 256] = o2;
        int bb = row >> 10, n = row & 1023;
        if (n == E_) {
            *(float4*)&outF[(size_t)bb * HSZ_ + c0]       = o1;
            *(float4*)&outF[(size_t)bb * HSZ_ + c0 + 256] = o2;
        }
    }
}

// ---------------------------------------------------------------------------
extern "C" void kernel_launch(void* const* d_in, const int* in_sizes, int n_in,
                              void* d_out, int out_size, void* d_ws, size_t ws_size,
                              hipStream_t stream) {
    const float* ents = (const float*)d_in[0];
    const int*   rels = (const int*)d_in[1];
    const int*   adj  = (const int*)d_in[2];
    const float* renc = (const float*)d_in[3];
    const float* Wq   = (const float*)d_in[4];
    const float* Wk   = (const float*)d_in[5];
    const float* Wv   = (const float*)d_in[6];
    const float* l1w  = (const float*)d_in[7];
    const float* l1b  = (const float*)d_in[8];
    const float* l2w  = (const float*)d_in[9];
    const float* l2b  = (const float*)d_in[10];
    const float* ln1s = (const float*)d_in[11];
    const float* ln1b = (const float*)d_in[12];
    const float* ln2s = (const float*)d_in[13];
    const float* ln2b = (const float*)d_in[14];
    const float* pa   = (const float*)d_in[15];

    char* ws = (char*)d_ws;
    size_t o = 0;
    auto alloc = [&](size_t bytes) { void* p = ws + o; o += bytes; return p; };
    bf16*     WqkvT  = (bf16*)alloc(3145728);   // per j: 1536 rows x 512 (Wq|Wk|Wv)^T
    bf16*     L1T    = (bf16*)alloc(4194304);
    bf16*     L2T    = (bf16*)alloc(4194304);
    unsigned* adjw   = (unsigned*)alloc(2097152);
    bf16*     xb     = (bf16*)alloc(16777216);
    bf16*     Qb     = (bf16*)alloc(16777216);
    bf16*     Kb     = (bf16*)alloc(16777216);
    bf16*     Vt     = (bf16*)alloc(16777216);
    bf16*     tb     = (bf16*)alloc(16777216);
    bf16*     hb     = (bf16*)alloc(67108864);
    float*    f32buf = (float*)alloc(33554432);
    if (o > ws_size) return;

    transpose_all<<<5632, 256, 0, stream>>>(Wq, Wk, Wv, l1w, l2w, WqkvT, L1T, L2T);
    pack_adj<<<65536, 256, 0, stream>>>(adj, adjw);
    build_x<<<4096, 256, 0, stream>>>(ents, rels, renc, xb);

    for (int j = 0; j < 2; j++) {
        gemm_bt<4><<<dim3(12, 128), 256, 0, stream>>>(xb, WqkvT + j * 786432, nullptr, nullptr, nullptr,
                                                      Qb, Kb, Vt, nullptr, 1536, 512);
        attn_fused<<<512, 256, 0, stream>>>(Qb, Kb, Vt, adjw, xb, f32buf);
        lnorm_k<0><<<4096, 256, 0, stream>>>(f32buf, ln1s + j * 512, ln1b + j * 512, tb, nullptr);
        gemm_bt<2><<<dim3(16, 128), 256, 0, stream>>>(tb, L1T + j * 1048576, l1b + j * 2048, pa + j * 2048,
                                                      nullptr, hb, nullptr, nullptr, nullptr, 2048, 512);
        gemm_bt<3><<<dim3(4, 128), 256, 0, stream>>>(hb, L2T + j * 1048576, l2b + j * 512, nullptr,
                                                     tb, nullptr, nullptr, nullptr, f32buf, 512, 2048);
        if (j == 0)
            lnorm_k<0><<<4096, 256, 0, stream>>>(f32buf, ln2s, ln2b, xb, nullptr);
        else
            lnorm_k<1><<<4112, 256, 0, stream>>>(f32buf, ln2s + 512, ln2b + 512, nullptr, (float*)d_out);
    }
}

// Round 15
// 617.352 us; speedup vs baseline: 1.1424x; 1.0348x over previous
//
#include <hip/hip_runtime.h>
#include <hip/hip_bf16.h>

typedef __bf16 bf16;
typedef __attribute__((ext_vector_type(8))) bf16 bf16x8;
typedef __attribute__((ext_vector_type(4))) float f32x4;

constexpr int B_   = 16;
constexpr int E_   = 400;
constexpr int R_   = 624;
constexpr int N_   = 1024;
constexpr int HSZ_ = 512;
constexpr int DFF_ = 2048;
constexpr int M_   = B_ * N_;

// global -> LDS direct DMA, 16B per lane (wave-uniform base + lane*16 dest).
__device__ __forceinline__ void glds16(const void* g, void* l) {
    __builtin_amdgcn_global_load_lds((const __attribute__((address_space(1))) void*)g,
                                     (__attribute__((address_space(3))) void*)l,
                                     16, 0, 0);
}

// ---------------------------------------------------------------------------
// R27 prologue: ONE launch for {10 weight transposes, adjacency bit-pack,
// x build} (was 3 launches -> 2 serial launch gaps removed). Block ranges:
//  [0,5632):        transposes (as R24)
//  [5632,22016):    pack_adj, 1 block per row, wave w handles col-groups
//                   4w..4w+3 via 4 coalesced strided loads + 4 ballots
//                   (4x fewer waves than the old 1-load-per-lane version)
//  [22016,26112):   build_x
__global__ __launch_bounds__(256) void prologue_k(const float* __restrict__ Wq,
                                                  const float* __restrict__ Wk,
                                                  const float* __restrict__ Wv,
                                                  const float* __restrict__ l1w,
                                                  const float* __restrict__ l2w,
                                                  const int*   __restrict__ adj,
                                                  const float* __restrict__ ents,
                                                  const int*   __restrict__ rels,
                                                  const float* __restrict__ renc,
                                                  bf16* __restrict__ WqkvT,
                                                  bf16* __restrict__ L1T,
                                                  bf16* __restrict__ L2T,
                                                  unsigned* __restrict__ adjw,
                                                  bf16* __restrict__ x) {
    int id = blockIdx.x;
    if (id < 5632) {
        __shared__ float tile[32][33];
        const float* in;
        bf16* out;
        int rows, cols, bx, by;
        if (id < 1536) {
            int grp = id >> 8;            // 0..5 = (j, {q,k,v})
            int loc = id & 255;
            bx = loc & 15; by = loc >> 4;
            rows = 512; cols = 512;
            int j = grp / 3, wsel = grp % 3;
            const float* W = (wsel == 0) ? Wq : (wsel == 1) ? Wk : Wv;
            in  = W + j * 262144;
            out = WqkvT + j * 786432 + wsel * 262144;
        } else if (id < 3584) {
            int loc = id - 1536;
            int j = loc >= 1024; loc &= 1023;
            bx = loc & 63; by = loc >> 6;
            rows = 512; cols = 2048;
            in  = l1w + j * 1048576;
            out = L1T + j * 1048576;
        } else {
            int loc = id - 3584;
            int j = loc >= 1024; loc &= 1023;
            bx = loc & 15; by = loc >> 4;
            rows = 2048; cols = 512;
            in  = l2w + j * 1048576;
            out = L2T + j * 1048576;
        }
        int tx = threadIdx.x & 31, ty = threadIdx.x >> 5;   // 32 x 8
        int c0 = bx * 32, r0 = by * 32;
        #pragma unroll
        for (int i = 0; i < 32; i += 8)
            tile[ty + i][tx] = in[(size_t)(r0 + ty + i) * cols + (c0 + tx)];
        __syncthreads();
        #pragma unroll
        for (int i = 0; i < 32; i += 8)
            out[(size_t)(c0 + ty + i) * rows + (r0 + tx)] = (bf16)tile[tx][ty + i];
    } else if (id < 22016) {
        int bn = id - 5632;                 // row 0..16383
        int w = threadIdx.x >> 6, L = threadIdx.x & 63;
        const int* rowp = adj + (size_t)bn * N_;
        #pragma unroll
        for (int i = 0; i < 4; i++) {
            int g = w * 4 + i;
            int v = rowp[g * 64 + L];
            unsigned long long mask = __ballot(v != 0);
            if (L == 0)  adjw[bn * 32 + g * 2]     = (unsigned)mask;
            if (L == 32) adjw[bn * 32 + g * 2 + 1] = (unsigned)(mask >> 32);
        }
    } else {
        int idx  = (id - 22016) * 256 + threadIdx.x;
        int col8 = (idx & 63) * 8;
        int row  = idx >> 6;
        int b = row >> 10, n = row & 1023;
        const float* src;
        if (n < E_) src = ents + ((size_t)(b * E_ + n)) * HSZ_ + col8;
        else {
            int rt = rels[b * R_ + (n - E_)];
            src = renc + (size_t)rt * HSZ_ + col8;
        }
        float4 a = *(const float4*)src;
        float4 c = *(const float4*)(src + 4);
        bf16x8 v;
        v[0] = (bf16)a.x; v[1] = (bf16)a.y; v[2] = (bf16)a.z; v[3] = (bf16)a.w;
        v[4] = (bf16)c.x; v[5] = (bf16)c.y; v[6] = (bf16)c.z; v[7] = (bf16)c.w;
        *(bf16x8*)(x + (size_t)row * HSZ_ + col8) = v;
    }
}

// ---------------------------------------------------------------------------
// GEMM v5 (PROVEN best, R10/R11/R13). 128x128 tile, BK=64, 4 waves, 256 thr.
// T1 bijective XCD swizzle (FETCH 69->17MB) + T2 both-sides XOR swizzle
// (conflicts 9.4M->0) + T4 counted-vmcnt dbuf (raw s_barrier, no vmcnt(0)
// drain in loop; sched_barrier(0) pins per rule #18).
// R26 ERRATA: 256^2 8-phase REGRESSED (65->95us) at these skinny shapes
// (FF2 grid 128 blocks = half GPU idle; 128KB LDS = 1 blk/CU kills m114
// implicit overlap; K=8 tiles can't amortize). 128^2/2-blk is the optimum.
// MODE 4: fused QKV — cols 0-511 -> outB (Qb), 512-1023 -> outB2 (Kb),
// 1024-1535 -> outB3 (Vt transposed). Branch is block-uniform.
template <int MODE>
__global__ __launch_bounds__(256) void gemm_bt(const bf16* __restrict__ A,
                                               const bf16* __restrict__ Bt,
                                               const float* __restrict__ biasF,
                                               const float* __restrict__ alphaF,
                                               const bf16* __restrict__ extraB,
                                               bf16* __restrict__ outB,
                                               bf16* __restrict__ outB2,
                                               bf16* __restrict__ outB3,
                                               float* __restrict__ outF,
                                               int Nn, int Kk) {
    __shared__ bf16 As[2][128][64];
    __shared__ bf16 Bs[2][128][64];

    int nwg = gridDim.x * gridDim.y;
    int bid = blockIdx.y * gridDim.x + blockIdx.x;   // dispatch order, x fastest
    int q = nwg >> 3;
    int ng = (bid & 7) * q + (bid >> 3);
    int bx = ng % gridDim.x, by = ng / gridDim.x;

    int n0 = bx * 128, m0 = by * 128;
    int t = threadIdx.x;
    int lane = t & 63, r = lane & 15, quad = lane >> 4;
    int w = t >> 6;
    int wm = w >> 1, wn = w & 1;

    int sRow = t >> 3;
    int xr   = sRow & 7;
    int sColL = (t & 7) * 8;                  // linear LDS chunk col
    int sColG = ((t & 7) ^ xr) * 8;           // pre-swizzled global chunk col
    const bf16* Ag = A  + (size_t)(m0 + sRow) * Kk + sColG;
    const bf16* Bg = Bt + (size_t)(n0 + sRow) * Kk + sColG;

#define G_STAGE(p_, k0_) do {                                          \
        glds16(Ag + (k0_),           &As[p_][sRow     ][sColL]);       \
        glds16(Ag + 32 * Kk + (k0_), &As[p_][sRow + 32][sColL]);       \
        glds16(Ag + 64 * Kk + (k0_), &As[p_][sRow + 64][sColL]);       \
        glds16(Ag + 96 * Kk + (k0_), &As[p_][sRow + 96][sColL]);       \
        glds16(Bg + (k0_),           &Bs[p_][sRow     ][sColL]);       \
        glds16(Bg + 32 * Kk + (k0_), &Bs[p_][sRow + 32][sColL]);       \
        glds16(Bg + 64 * Kk + (k0_), &Bs[p_][sRow + 64][sColL]);       \
        glds16(Bg + 96 * Kk + (k0_), &Bs[p_][sRow + 96][sColL]);       \
    } while (0)

    f32x4 acc[4][4];
    #pragma unroll
    for (int mt = 0; mt < 4; mt++)
        #pragma unroll
        for (int nt = 0; nt < 4; nt++) acc[mt][nt] = (f32x4){0.f, 0.f, 0.f, 0.f};

    int xa = r & 7;   // read-side swizzle key: fragment rows -> row&7 = r&7

    G_STAGE(0, 0);
    int ntiles = Kk >> 6;
    for (int tt = 0; tt < ntiles; tt++) {
        int p = tt & 1;
        if (tt + 1 < ntiles) {
            G_STAGE(p ^ 1, (tt + 1) * 64);              // 8 new loads in flight
            asm volatile("s_waitcnt vmcnt(8)" ::: "memory");  // tile t landed
        } else {
            asm volatile("s_waitcnt vmcnt(0)" ::: "memory");  // epilogue drain
        }
        __builtin_amdgcn_s_barrier();                   // raw: no vmcnt(0)
        __builtin_amdgcn_sched_barrier(0);
        #pragma unroll
        for (int kk = 0; kk < 64; kk += 32) {
            int pc = (((kk >> 3) + quad) ^ xa) * 8;
            bf16x8 af[4], bfr[4];
            #pragma unroll
            for (int mt = 0; mt < 4; mt++)
                af[mt] = *(const bf16x8*)&As[p][wm * 64 + mt * 16 + r][pc];
            #pragma unroll
            for (int nt = 0; nt < 4; nt++)
                bfr[nt] = *(const bf16x8*)&Bs[p][wn * 64 + nt * 16 + r][pc];
            #pragma unroll
            for (int mt = 0; mt < 4; mt++)
                #pragma unroll
                for (int nt = 0; nt < 4; nt++)
                    acc[mt][nt] = __builtin_amdgcn_mfma_f32_16x16x32_bf16(af[mt], bfr[nt], acc[mt][nt], 0, 0, 0);
        }
        __builtin_amdgcn_s_barrier();                   // buf[p] reads done
        __builtin_amdgcn_sched_barrier(0);              // pin: no stage hoist
    }
#undef G_STAGE

    #pragma unroll
    for (int mt = 0; mt < 4; mt++) {
        #pragma unroll
        for (int nt = 0; nt < 4; nt++) {
            #pragma unroll
            for (int i = 0; i < 4; i++) {
                int rg = m0 + wm * 64 + mt * 16 + quad * 4 + i;
                int cg = n0 + wn * 64 + nt * 16 + r;
                float v = acc[mt][nt][i];
                if (MODE == 0) {
                    outB[(size_t)rg * Nn + cg] = (bf16)v;
                } else if (MODE == 1) {
                    int bb = rg >> 10, n = rg & 1023;
                    outB[(size_t)(bb * HSZ_ + cg) * N_ + n] = (bf16)v;
                } else if (MODE == 2) {
                    v += biasF[cg];
                    float a = alphaF[cg];
                    v = v > 0.f ? v : a * v;
                    outB[(size_t)rg * Nn + cg] = (bf16)v;
                } else if (MODE == 3) {
                    v += biasF[cg] + (float)extraB[(size_t)rg * Nn + cg];
                    outF[(size_t)rg * Nn + cg] = v;
                } else {   // MODE 4: fused QKV
                    if (cg < 512) {
                        outB[(size_t)rg * HSZ_ + cg] = (bf16)v;
                    } else if (cg < 1024) {
                        outB2[(size_t)rg * HSZ_ + (cg - 512)] = (bf16)v;
                    } else {
                        int bb = rg >> 10, n = rg & 1023;
                        outB3[(size_t)(bb * HSZ_ + (cg - 1024)) * N_ + n] = (bf16)v;
                    }
                }
            }
        }
    }
}

// ---------------------------------------------------------------------------
// Fused MFMA attention v12 (R27): = v11 + folded exp2 softmax.
// exp(x*scale - SHIFT) == exp2(x*scale2 - SHIFT2) with scale2=scale*log2e,
// SHIFT2=SHIFT*log2e -> one v_fma + v_exp per p (was mul/sub/mul/exp);
// 32 exps per thread-iter on the 36%-VALUBusy hot path. SHIFT2 cancels
// between P and l exactly as SHIFT did.
// v11 core: T14 single prefetch set of 8 NAMED uint4 scalars; issue(it+1)
// right after the staging barrier; T5 setprio around MFMA clusters.
__global__ __launch_bounds__(256) void attn_fused(const bf16* __restrict__ Q,
                                                  const bf16* __restrict__ K,
                                                  const bf16* __restrict__ Vt,
                                                  const unsigned* __restrict__ adjw,
                                                  const bf16* __restrict__ xb,
                                                  float* __restrict__ tpre) {
    int blk = blockIdx.x;
    int gr = blk & 7;
    int qb = (blk >> 3) & 7;
    int gq = blk >> 6;
    int g = gq * 8 + gr;
    int b = g >> 2, h = g & 3;

    int tid = threadIdx.x;
    int w = tid >> 6, lane = tid & 63;
    int r = lane & 15, quad = lane >> 4;
    int n0 = qb * 128 + w * 32;      // this wave's 32 q-rows (2 m-tiles)

    __shared__ bf16 Ks[64][136];     // [key][dim], +8 pad -> 2-way (free)
    __shared__ bf16 Vs[128][72];     // [dim][key], +8 pad -> 2-way (free)
    __shared__ bf16 plds[4][32][68]; // per-wave P tile, padded

    int kRow = tid >> 4, kCol = (tid & 15) * 8;
    int vRow = tid >> 3, vCol = (tid & 7) * 8;
    const bf16* Kg = K + (size_t)(b * N_) * HSZ_ + h * 128 + (size_t)kRow * HSZ_ + kCol;
    const bf16* Vg = Vt + (size_t)(b * HSZ_ + h * 128 + vRow) * N_ + vCol;
    bf16* KsP = &Ks[kRow][kCol];
    bf16* VsP = &Vs[vRow][vCol];

    // single prefetch set: 8 named uint4 (rule #20: no arrays, no addr-taken)
    uint4 kp0, kp1, kp2, kp3, vp0, vp1, vp2, vp3;

#define ATTN_ISSUE(it_) do {                                                      \
        const bf16* kg_ = Kg + (size_t)(it_) * 64 * HSZ_;                         \
        const bf16* vg_ = Vg + (it_) * 64;                                        \
        kp0 = *(const uint4*)(kg_);                                               \
        kp1 = *(const uint4*)(kg_ + 16 * HSZ_);                                   \
        kp2 = *(const uint4*)(kg_ + 32 * HSZ_);                                   \
        kp3 = *(const uint4*)(kg_ + 48 * HSZ_);                                   \
        vp0 = *(const uint4*)(vg_);                                               \
        vp1 = *(const uint4*)(vg_ + 32 * N_);                                     \
        vp2 = *(const uint4*)(vg_ + 64 * N_);                                     \
        vp3 = *(const uint4*)(vg_ + 96 * N_);                                     \
    } while (0)

#define ATTN_COMMIT() do {                                                        \
        *(uint4*)(KsP)            = kp0;                                          \
        *(uint4*)(KsP + 16 * 136) = kp1;                                          \
        *(uint4*)(KsP + 32 * 136) = kp2;                                          \
        *(uint4*)(KsP + 48 * 136) = kp3;                                          \
        *(uint4*)(VsP)            = vp0;                                          \
        *(uint4*)(VsP + 32 * 72)  = vp1;                                          \
        *(uint4*)(VsP + 64 * 72)  = vp2;                                          \
        *(uint4*)(VsP + 96 * 72)  = vp3;                                          \
    } while (0)

    bf16x8 qf[2][4];
    #pragma unroll
    for (int mt = 0; mt < 2; mt++) {
        const bf16* qbase = Q + ((size_t)(b * N_ + n0 + mt * 16 + r)) * HSZ_ + h * 128;
        #pragma unroll
        for (int kc = 0; kc < 4; kc++) qf[mt][kc] = *(const bf16x8*)(qbase + kc * 32 + quad * 8);
    }

    f32x4 accv[2][8];
    #pragma unroll
    for (int mt = 0; mt < 2; mt++)
        #pragma unroll
        for (int dt = 0; dt < 8; dt++) accv[mt][dt] = (f32x4){0.f, 0.f, 0.f, 0.f};
    float tl[2][4] = {{0.f, 0.f, 0.f, 0.f}, {0.f, 0.f, 0.f, 0.f}};
    const float scale2 = 0.04419417382415922f * 1.4426950408889634f;  // scale*log2e
    const float SHIFT2 = 12.0f * 1.4426950408889634f;                 // cancels in P/l

    ATTN_ISSUE(0);
    for (int it = 0; it < 16; it++) {
        __syncthreads();               // all waves done reading Ks/Vs
        ATTN_COMMIT();                 // waits vmcnt for the prefetch set
        __syncthreads();               // staging visible
        if (it + 1 < 16) ATTN_ISSUE(it + 1);   // flies under compute

        // QK^T: 4 groups of 16 keys; K-fragment shared by both m-tiles
        f32x4 cg[2][4];
        #pragma unroll
        for (int mt = 0; mt < 2; mt++)
            #pragma unroll
            for (int gk = 0; gk < 4; gk++) cg[mt][gk] = (f32x4){0.f, 0.f, 0.f, 0.f};
        __builtin_amdgcn_s_setprio(1);
        #pragma unroll
        for (int gk = 0; gk < 4; gk++)
            #pragma unroll
            for (int kc = 0; kc < 4; kc++) {
                bf16x8 kf = *(const bf16x8*)&Ks[gk * 16 + r][kc * 32 + quad * 8];
                cg[0][gk] = __builtin_amdgcn_mfma_f32_16x16x32_bf16(qf[0][kc], kf, cg[0][gk], 0, 0, 0);
                cg[1][gk] = __builtin_amdgcn_mfma_f32_16x16x32_bf16(qf[1][kc], kf, cg[1][gk], 0, 0, 0);
            }
        __builtin_amdgcn_s_setprio(0);
        // mask + exp2 -> plds + tl
        #pragma unroll
        for (int mt = 0; mt < 2; mt++)
            #pragma unroll
            for (int i = 0; i < 4; i++) {
                int row_l = mt * 16 + quad * 4 + i;
                int row_g = n0 + row_l;
                const unsigned* aw = &adjw[((size_t)(b << 10) + row_g) * 32 + it * 2];
                unsigned wb0 = aw[0], wb1 = aw[1];
                float p0 = ((wb0 >> r) & 1u)        ? exp2f(cg[mt][0][i] * scale2 - SHIFT2) : 0.f;
                float p1 = ((wb0 >> (16 + r)) & 1u) ? exp2f(cg[mt][1][i] * scale2 - SHIFT2) : 0.f;
                float p2 = ((wb1 >> r) & 1u)        ? exp2f(cg[mt][2][i] * scale2 - SHIFT2) : 0.f;
                float p3 = ((wb1 >> (16 + r)) & 1u) ? exp2f(cg[mt][3][i] * scale2 - SHIFT2) : 0.f;
                tl[mt][i] += p0 + p1 + p2 + p3;
                plds[w][row_l][r]      = (bf16)p0;
                plds[w][row_l][16 + r] = (bf16)p1;
                plds[w][row_l][32 + r] = (bf16)p2;
                plds[w][row_l][48 + r] = (bf16)p3;
            }
        // no barrier: plds[w] is wave-private; same-wave DS ordering suffices

        // PV: P (A-op, 64 keys in 2 k-chunks) x Vs; V-fragments shared
        bf16x8 pf00 = *(const bf16x8*)&plds[w][r][quad * 8];
        bf16x8 pf01 = *(const bf16x8*)&plds[w][r][32 + quad * 8];
        bf16x8 pf10 = *(const bf16x8*)&plds[w][16 + r][quad * 8];
        bf16x8 pf11 = *(const bf16x8*)&plds[w][16 + r][32 + quad * 8];
        __builtin_amdgcn_s_setprio(1);
        #pragma unroll
        for (int dt = 0; dt < 8; dt++) {
            bf16x8 v0 = *(const bf16x8*)&Vs[dt * 16 + r][quad * 8];
            bf16x8 v1 = *(const bf16x8*)&Vs[dt * 16 + r][32 + quad * 8];
            accv[0][dt] = __builtin_amdgcn_mfma_f32_16x16x32_bf16(pf00, v0, accv[0][dt], 0, 0, 0);
            accv[0][dt] = __builtin_amdgcn_mfma_f32_16x16x32_bf16(pf01, v1, accv[0][dt], 0, 0, 0);
            accv[1][dt] = __builtin_amdgcn_mfma_f32_16x16x32_bf16(pf10, v0, accv[1][dt], 0, 0, 0);
            accv[1][dt] = __builtin_amdgcn_mfma_f32_16x16x32_bf16(pf11, v1, accv[1][dt], 0, 0, 0);
        }
        __builtin_amdgcn_s_setprio(0);
    }
#undef ATTN_ISSUE
#undef ATTN_COMMIT

    // per-wave epilogue
    #pragma unroll
    for (int mt = 0; mt < 2; mt++)
        #pragma unroll
        for (int i = 0; i < 4; i++) {
            float l = tl[mt][i];
            #pragma unroll
            for (int d = 1; d < 16; d <<= 1) l += __shfl_xor(l, d, 64);
            float inv_l = 1.0f / fmaxf(l, 1e-30f);
            #pragma unroll
            for (int dt = 0; dt < 8; dt++) {
                int row = n0 + mt * 16 + quad * 4 + i;
                int col = h * 128 + dt * 16 + r;
                size_t idx = ((size_t)(b * N_ + row)) * HSZ_ + col;
                tpre[idx] = accv[mt][dt][i] * inv_l + (float)xb[idx];
            }
        }
}

// ---------------------------------------------------------------------------
// wave-per-row layernorm, 4 rows/block. OUT=0: bf16 to outB (intermediate).
// OUT=1: final lnorm2 of j=1 writes f32 directly to d_out (nodes + glob
// duplicate at n==E_); blocks >= 4096 fill node_mask with 1.0f.
template <int OUT>
__global__ __launch_bounds__(256) void lnorm_k(const float* __restrict__ in,
                                               const float* __restrict__ sc,
                                               const float* __restrict__ bi,
                                               bf16* __restrict__ outB,
                                               float* __restrict__ outF) {
    if (OUT == 1 && blockIdx.x >= 4096) {
        int idx = (blockIdx.x - 4096) * 1024 + threadIdx.x * 4;
        float4 one = {1.f, 1.f, 1.f, 1.f};
        *(float4*)&outF[(size_t)B_ * HSZ_ + (size_t)B_ * N_ * HSZ_ + idx] = one;
        return;
    }
    int row = blockIdx.x * 4 + (threadIdx.x >> 6);
    int lane = threadIdx.x & 63;
    const float* rp = in + (size_t)row * HSZ_;
    float4 a = *(const float4*)(rp + lane * 4);
    float4 b = *(const float4*)(rp + 256 + lane * 4);
    float sum = a.x + a.y + a.z + a.w + b.x + b.y + b.z + b.w;
    float sq  = a.x*a.x + a.y*a.y + a.z*a.z + a.w*a.w
              + b.x*b.x + b.y*b.y + b.z*b.z + b.w*b.w;
    #pragma unroll
    for (int d = 1; d < 64; d <<= 1) {
        sum += __shfl_xor(sum, d, 64);
        sq  += __shfl_xor(sq,  d, 64);
    }
    float mu = sum * (1.0f / HSZ_);
    float varv = fmaxf(sq * (1.0f / HSZ_) - mu * mu, 0.f);
    float rs = rsqrtf(varv + 1e-5f);
    int c0 = lane * 4;
    float va[4] = {a.x, a.y, a.z, a.w}, vb[4] = {b.x, b.y, b.z, b.w};
    if (OUT == 0) {
        bf16* op = outB + (size_t)row * HSZ_;
        #pragma unroll
        for (int k = 0; k < 4; k++) {
            op[c0 + k]       = (bf16)(((va[k] - mu) * rs) * sc[c0 + k] + bi[c0 + k]);
            op[c0 + 256 + k] = (bf16)(((vb[k] - mu) * rs) * sc[c0 + 256 + k] + bi[c0 + 256 + k]);
        }
    } else {
        float4 o1, o2;
        o1.x = ((va[0] - mu) * rs) * sc[c0 + 0] + bi[c0 + 0];
        o1.y = ((va[1] - mu) * rs) * sc[c0 + 1] + bi[c0 + 1];
        o1.z = ((va[2] - mu) * rs) * sc[c0 + 2] + bi[c0 + 2];
        o1.w = ((va[3] - mu) * rs) * sc[c0 + 3] + bi[c0 + 3];
        o2.x = ((vb[0] - mu) * rs) * sc[c0 + 256] + bi[c0 + 256];
        o2.y = ((vb[1] - mu) * rs) * sc[c0 + 257] + bi[c0 + 257];
        o2.z = ((vb[2] - mu) * rs) * sc[c0 + 258] + bi[c0 + 258];
        o2.w = ((vb[3] - mu) * rs) * sc[c0 + 259] + bi[c0 + 259];
        float* nodes = outF + (size_t)B_ * HSZ_;
        *(float4*)&nodes[(size_t)row * HSZ_ + c0]       = o1;
        *(float4*)&nodes[(size_t)row * HSZ_ + c0 + 256] = o2;
        int bb = row >> 10, n = row & 1023;
        if (n == E_) {
            *(float4*)&outF[(size_t)bb * HSZ_ + c0]       = o1;
            *(float4*)&outF[(size_t)bb * HSZ_ + c0 + 256] = o2;
        }
    }
}

// ---------------------------------------------------------------------------
extern "C" void kernel_launch(void* const* d_in, const int* in_sizes, int n_in,
                              void* d_out, int out_size, void* d_ws, size_t ws_size,
                              hipStream_t stream) {
    const float* ents = (const float*)d_in[0];
    const int*   rels = (const int*)d_in[1];
    const int*   adj  = (const int*)d_in[2];
    const float* renc = (const float*)d_in[3];
    const float* Wq   = (const float*)d_in[4];
    const float* Wk   = (const float*)d_in[5];
    const float* Wv   = (const float*)d_in[6];
    const float* l1w  = (const float*)d_in[7];
    const float* l1b  = (const float*)d_in[8];
    const float* l2w  = (const float*)d_in[9];
    const float* l2b  = (const float*)d_in[10];
    const float* ln1s = (const float*)d_in[11];
    const float* ln1b = (const float*)d_in[12];
    const float* ln2s = (const float*)d_in[13];
    const float* ln2b = (const float*)d_in[14];
    const float* pa   = (const float*)d_in[15];

    char* ws = (char*)d_ws;
    size_t o = 0;
    auto alloc = [&](size_t bytes) { void* p = ws + o; o += bytes; return p; };
    bf16*     WqkvT  = (bf16*)alloc(3145728);   // per j: 1536 rows x 512 (Wq|Wk|Wv)^T
    bf16*     L1T    = (bf16*)alloc(4194304);
    bf16*     L2T    = (bf16*)alloc(4194304);
    unsigned* adjw   = (unsigned*)alloc(2097152);
    bf16*     xb     = (bf16*)alloc(16777216);
    bf16*     Qb     = (bf16*)alloc(16777216);
    bf16*     Kb     = (bf16*)alloc(16777216);
    bf16*     Vt     = (bf16*)alloc(16777216);
    bf16*     tb     = (bf16*)alloc(16777216);
    bf16*     hb     = (bf16*)alloc(67108864);
    float*    f32buf = (float*)alloc(33554432);
    if (o > ws_size) return;

    prologue_k<<<26112, 256, 0, stream>>>(Wq, Wk, Wv, l1w, l2w, adj, ents, rels, renc,
                                          WqkvT, L1T, L2T, adjw, xb);

    for (int j = 0; j < 2; j++) {
        gemm_bt<4><<<dim3(12, 128), 256, 0, stream>>>(xb, WqkvT + j * 786432, nullptr, nullptr, nullptr,
                                                      Qb, Kb, Vt, nullptr, 1536, 512);
        attn_fused<<<512, 256, 0, stream>>>(Qb, Kb, Vt, adjw, xb, f32buf);
        lnorm_k<0><<<4096, 256, 0, stream>>>(f32buf, ln1s + j * 512, ln1b + j * 512, tb, nullptr);
        gemm_bt<2><<<dim3(16, 128), 256, 0, stream>>>(tb, L1T + j * 1048576, l1b + j * 2048, pa + j * 2048,
                                                      nullptr, hb, nullptr, nullptr, nullptr, 2048, 512);
        gemm_bt<3><<<dim3(4, 128), 256, 0, stream>>>(hb, L2T + j * 1048576, l2b + j * 512, nullptr,
                                                     tb, nullptr, nullptr, nullptr, f32buf, 512, 2048);
        if (j == 0)
            lnorm_k<0><<<4096, 256, 0, stream>>>(f32buf, ln2s, ln2b, xb, nullptr);
        else
            lnorm_k<1><<<4112, 256, 0, stream>>>(f32buf, ln2s + 512, ln2b + 512, nullptr, (float*)d_out);
    }
}

// Round 16
// 615.371 us; speedup vs baseline: 1.1460x; 1.0032x over previous
//
#include <hip/hip_runtime.h>
#include <hip/hip_bf16.h>

typedef __bf16 bf16;
typedef __attribute__((ext_vector_type(8))) bf16 bf16x8;
typedef __attribute__((ext_vector_type(4))) float f32x4;

constexpr int B_   = 16;
constexpr int E_   = 400;
constexpr int R_   = 624;
constexpr int N_   = 1024;
constexpr int HSZ_ = 512;
constexpr int DFF_ = 2048;
constexpr int M_   = B_ * N_;

// global -> LDS direct DMA, 16B per lane (wave-uniform base + lane*16 dest).
__device__ __forceinline__ void glds16(const void* g, void* l) {
    __builtin_amdgcn_global_load_lds((const __attribute__((address_space(1))) void*)g,
                                     (__attribute__((address_space(3))) void*)l,
                                     16, 0, 0);
}

// ---------------------------------------------------------------------------
// Prologue: ONE launch for {10 weight transposes, adjacency bit-pack, x build}.
//  [0,5632):      transposes
//  [5632,22016):  pack_adj (4x vectorized: wave handles 4 col-groups)
//  [22016,26112): build_x
__global__ __launch_bounds__(256) void prologue_k(const float* __restrict__ Wq,
                                                  const float* __restrict__ Wk,
                                                  const float* __restrict__ Wv,
                                                  const float* __restrict__ l1w,
                                                  const float* __restrict__ l2w,
                                                  const int*   __restrict__ adj,
                                                  const float* __restrict__ ents,
                                                  const int*   __restrict__ rels,
                                                  const float* __restrict__ renc,
                                                  bf16* __restrict__ WqkvT,
                                                  bf16* __restrict__ L1T,
                                                  bf16* __restrict__ L2T,
                                                  unsigned* __restrict__ adjw,
                                                  bf16* __restrict__ x) {
    int id = blockIdx.x;
    if (id < 5632) {
        __shared__ float tile[32][33];
        const float* in;
        bf16* out;
        int rows, cols, bx, by;
        if (id < 1536) {
            int grp = id >> 8;            // 0..5 = (j, {q,k,v})
            int loc = id & 255;
            bx = loc & 15; by = loc >> 4;
            rows = 512; cols = 512;
            int j = grp / 3, wsel = grp % 3;
            const float* W = (wsel == 0) ? Wq : (wsel == 1) ? Wk : Wv;
            in  = W + j * 262144;
            out = WqkvT + j * 786432 + wsel * 262144;
        } else if (id < 3584) {
            int loc = id - 1536;
            int j = loc >= 1024; loc &= 1023;
            bx = loc & 63; by = loc >> 6;
            rows = 512; cols = 2048;
            in  = l1w + j * 1048576;
            out = L1T + j * 1048576;
        } else {
            int loc = id - 3584;
            int j = loc >= 1024; loc &= 1023;
            bx = loc & 15; by = loc >> 4;
            rows = 2048; cols = 512;
            in  = l2w + j * 1048576;
            out = L2T + j * 1048576;
        }
        int tx = threadIdx.x & 31, ty = threadIdx.x >> 5;   // 32 x 8
        int c0 = bx * 32, r0 = by * 32;
        #pragma unroll
        for (int i = 0; i < 32; i += 8)
            tile[ty + i][tx] = in[(size_t)(r0 + ty + i) * cols + (c0 + tx)];
        __syncthreads();
        #pragma unroll
        for (int i = 0; i < 32; i += 8)
            out[(size_t)(c0 + ty + i) * rows + (r0 + tx)] = (bf16)tile[tx][ty + i];
    } else if (id < 22016) {
        int bn = id - 5632;                 // row 0..16383
        int w = threadIdx.x >> 6, L = threadIdx.x & 63;
        const int* rowp = adj + (size_t)bn * N_;
        #pragma unroll
        for (int i = 0; i < 4; i++) {
            int g = w * 4 + i;
            int v = rowp[g * 64 + L];
            unsigned long long mask = __ballot(v != 0);
            if (L == 0)  adjw[bn * 32 + g * 2]     = (unsigned)mask;
            if (L == 32) adjw[bn * 32 + g * 2 + 1] = (unsigned)(mask >> 32);
        }
    } else {
        int idx  = (id - 22016) * 256 + threadIdx.x;
        int col8 = (idx & 63) * 8;
        int row  = idx >> 6;
        int b = row >> 10, n = row & 1023;
        const float* src;
        if (n < E_) src = ents + ((size_t)(b * E_ + n)) * HSZ_ + col8;
        else {
            int rt = rels[b * R_ + (n - E_)];
            src = renc + (size_t)rt * HSZ_ + col8;
        }
        float4 a = *(const float4*)src;
        float4 c = *(const float4*)(src + 4);
        bf16x8 v;
        v[0] = (bf16)a.x; v[1] = (bf16)a.y; v[2] = (bf16)a.z; v[3] = (bf16)a.w;
        v[4] = (bf16)c.x; v[5] = (bf16)c.y; v[6] = (bf16)c.z; v[7] = (bf16)c.w;
        *(bf16x8*)(x + (size_t)row * HSZ_ + col8) = v;
    }
}

// ---------------------------------------------------------------------------
// GEMM v5 (PROVEN best). 128x128 tile, BK=64, 4 waves, 256 thr.
// T1 bijective XCD swizzle (FETCH 69->17MB) + T2 both-sides XOR swizzle
// (conflicts 9.4M->0) + T4 counted-vmcnt dbuf (raw s_barrier; sched_barrier
// pins per rule #18). R26 ERRATA: 256^2 8-phase regressed at these shapes.
// MODE 4: fused QKV; MODE 2: bias+PReLU bf16; MODE 3: bias+residual f32.
template <int MODE>
__global__ __launch_bounds__(256) void gemm_bt(const bf16* __restrict__ A,
                                               const bf16* __restrict__ Bt,
                                               const float* __restrict__ biasF,
                                               const float* __restrict__ alphaF,
                                               const bf16* __restrict__ extraB,
                                               bf16* __restrict__ outB,
                                               bf16* __restrict__ outB2,
                                               bf16* __restrict__ outB3,
                                               float* __restrict__ outF,
                                               int Nn, int Kk) {
    __shared__ bf16 As[2][128][64];
    __shared__ bf16 Bs[2][128][64];

    int nwg = gridDim.x * gridDim.y;
    int bid = blockIdx.y * gridDim.x + blockIdx.x;   // dispatch order, x fastest
    int q = nwg >> 3;
    int ng = (bid & 7) * q + (bid >> 3);
    int bx = ng % gridDim.x, by = ng / gridDim.x;

    int n0 = bx * 128, m0 = by * 128;
    int t = threadIdx.x;
    int lane = t & 63, r = lane & 15, quad = lane >> 4;
    int w = t >> 6;
    int wm = w >> 1, wn = w & 1;

    int sRow = t >> 3;
    int xr   = sRow & 7;
    int sColL = (t & 7) * 8;                  // linear LDS chunk col
    int sColG = ((t & 7) ^ xr) * 8;           // pre-swizzled global chunk col
    const bf16* Ag = A  + (size_t)(m0 + sRow) * Kk + sColG;
    const bf16* Bg = Bt + (size_t)(n0 + sRow) * Kk + sColG;

#define G_STAGE(p_, k0_) do {                                          \
        glds16(Ag + (k0_),           &As[p_][sRow     ][sColL]);       \
        glds16(Ag + 32 * Kk + (k0_), &As[p_][sRow + 32][sColL]);       \
        glds16(Ag + 64 * Kk + (k0_), &As[p_][sRow + 64][sColL]);       \
        glds16(Ag + 96 * Kk + (k0_), &As[p_][sRow + 96][sColL]);       \
        glds16(Bg + (k0_),           &Bs[p_][sRow     ][sColL]);       \
        glds16(Bg + 32 * Kk + (k0_), &Bs[p_][sRow + 32][sColL]);       \
        glds16(Bg + 64 * Kk + (k0_), &Bs[p_][sRow + 64][sColL]);       \
        glds16(Bg + 96 * Kk + (k0_), &Bs[p_][sRow + 96][sColL]);       \
    } while (0)

    f32x4 acc[4][4];
    #pragma unroll
    for (int mt = 0; mt < 4; mt++)
        #pragma unroll
        for (int nt = 0; nt < 4; nt++) acc[mt][nt] = (f32x4){0.f, 0.f, 0.f, 0.f};

    int xa = r & 7;   // read-side swizzle key: fragment rows -> row&7 = r&7

    G_STAGE(0, 0);
    int ntiles = Kk >> 6;
    for (int tt = 0; tt < ntiles; tt++) {
        int p = tt & 1;
        if (tt + 1 < ntiles) {
            G_STAGE(p ^ 1, (tt + 1) * 64);              // 8 new loads in flight
            asm volatile("s_waitcnt vmcnt(8)" ::: "memory");  // tile t landed
        } else {
            asm volatile("s_waitcnt vmcnt(0)" ::: "memory");  // epilogue drain
        }
        __builtin_amdgcn_s_barrier();                   // raw: no vmcnt(0)
        __builtin_amdgcn_sched_barrier(0);
        #pragma unroll
        for (int kk = 0; kk < 64; kk += 32) {
            int pc = (((kk >> 3) + quad) ^ xa) * 8;
            bf16x8 af[4], bfr[4];
            #pragma unroll
            for (int mt = 0; mt < 4; mt++)
                af[mt] = *(const bf16x8*)&As[p][wm * 64 + mt * 16 + r][pc];
            #pragma unroll
            for (int nt = 0; nt < 4; nt++)
                bfr[nt] = *(const bf16x8*)&Bs[p][wn * 64 + nt * 16 + r][pc];
            #pragma unroll
            for (int mt = 0; mt < 4; mt++)
                #pragma unroll
                for (int nt = 0; nt < 4; nt++)
                    acc[mt][nt] = __builtin_amdgcn_mfma_f32_16x16x32_bf16(af[mt], bfr[nt], acc[mt][nt], 0, 0, 0);
        }
        __builtin_amdgcn_s_barrier();                   // buf[p] reads done
        __builtin_amdgcn_sched_barrier(0);              // pin: no stage hoist
    }
#undef G_STAGE

    #pragma unroll
    for (int mt = 0; mt < 4; mt++) {
        #pragma unroll
        for (int nt = 0; nt < 4; nt++) {
            #pragma unroll
            for (int i = 0; i < 4; i++) {
                int rg = m0 + wm * 64 + mt * 16 + quad * 4 + i;
                int cg = n0 + wn * 64 + nt * 16 + r;
                float v = acc[mt][nt][i];
                if (MODE == 0) {
                    outB[(size_t)rg * Nn + cg] = (bf16)v;
                } else if (MODE == 1) {
                    int bb = rg >> 10, n = rg & 1023;
                    outB[(size_t)(bb * HSZ_ + cg) * N_ + n] = (bf16)v;
                } else if (MODE == 2) {
                    v += biasF[cg];
                    float a = alphaF[cg];
                    v = v > 0.f ? v : a * v;
                    outB[(size_t)rg * Nn + cg] = (bf16)v;
                } else if (MODE == 3) {
                    v += biasF[cg] + (float)extraB[(size_t)rg * Nn + cg];
                    outF[(size_t)rg * Nn + cg] = v;
                } else {   // MODE 4: fused QKV
                    if (cg < 512) {
                        outB[(size_t)rg * HSZ_ + cg] = (bf16)v;
                    } else if (cg < 1024) {
                        outB2[(size_t)rg * HSZ_ + (cg - 512)] = (bf16)v;
                    } else {
                        int bb = rg >> 10, n = rg & 1023;
                        outB3[(size_t)(bb * HSZ_ + (cg - 1024)) * N_ + n] = (bf16)v;
                    }
                }
            }
        }
    }
}

// ---------------------------------------------------------------------------
// Fused MFMA attention v13 (R28): = v12 + adjacency-mask prefetch.
// v12 counters: MfmaUtil 19 / VALU 45 / HBM 12.6 -- mixed latency+VALU.
// Remaining exposed latency: 16 scalar VMEM mask loads per thread-iter
// issued BETWEEN QK^T and softmax (L2 ~200cyc naked on the critical path;
// K/V are prefetched an iter ahead, masks were not). v13 prefetches masks
// for it+1 inside ATTN_ISSUE as 8 named uint2 (8B loads, was 2x dword),
// copies to 8 named current regs before the next issue (rule #20: named
// scalars only). +32 VGPR (~160) -- free at 2 blk/CU.
__global__ __launch_bounds__(256) void attn_fused(const bf16* __restrict__ Q,
                                                  const bf16* __restrict__ K,
                                                  const bf16* __restrict__ Vt,
                                                  const unsigned* __restrict__ adjw,
                                                  const bf16* __restrict__ xb,
                                                  float* __restrict__ tpre) {
    int blk = blockIdx.x;
    int gr = blk & 7;
    int qb = (blk >> 3) & 7;
    int gq = blk >> 6;
    int g = gq * 8 + gr;
    int b = g >> 2, h = g & 3;

    int tid = threadIdx.x;
    int w = tid >> 6, lane = tid & 63;
    int r = lane & 15, quad = lane >> 4;
    int n0 = qb * 128 + w * 32;      // this wave's 32 q-rows (2 m-tiles)

    __shared__ bf16 Ks[64][136];     // [key][dim], +8 pad -> 2-way (free)
    __shared__ bf16 Vs[128][72];     // [dim][key], +8 pad -> 2-way (free)
    __shared__ bf16 plds[4][32][68]; // per-wave P tile, padded

    int kRow = tid >> 4, kCol = (tid & 15) * 8;
    int vRow = tid >> 3, vCol = (tid & 7) * 8;
    const bf16* Kg = K + (size_t)(b * N_) * HSZ_ + h * 128 + (size_t)kRow * HSZ_ + kCol;
    const bf16* Vg = Vt + (size_t)(b * HSZ_ + h * 128 + vRow) * N_ + vCol;
    bf16* KsP = &Ks[kRow][kCol];
    bf16* VsP = &Vs[vRow][vCol];
    // mask base for this thread's 8 rows: row(mt,i) = n0 + mt*16 + quad*4 + i
    const unsigned* Aw = adjw + ((size_t)(b << 10) + n0 + quad * 4) * 32;

    // prefetch sets: named scalars only (rule #20)
    uint4 kp0, kp1, kp2, kp3, vp0, vp1, vp2, vp3;
    uint2 pm00, pm01, pm02, pm03, pm10, pm11, pm12, pm13;   // masks, next iter
    uint2 cm00, cm01, cm02, cm03, cm10, cm11, cm12, cm13;   // masks, this iter

#define ATTN_ISSUE(it_) do {                                                      \
        const bf16* kg_ = Kg + (size_t)(it_) * 64 * HSZ_;                         \
        const bf16* vg_ = Vg + (it_) * 64;                                        \
        kp0 = *(const uint4*)(kg_);                                               \
        kp1 = *(const uint4*)(kg_ + 16 * HSZ_);                                   \
        kp2 = *(const uint4*)(kg_ + 32 * HSZ_);                                   \
        kp3 = *(const uint4*)(kg_ + 48 * HSZ_);                                   \
        vp0 = *(const uint4*)(vg_);                                               \
        vp1 = *(const uint4*)(vg_ + 32 * N_);                                     \
        vp2 = *(const uint4*)(vg_ + 64 * N_);                                     \
        vp3 = *(const uint4*)(vg_ + 96 * N_);                                     \
        const unsigned* aw_ = Aw + (it_) * 2;                                     \
        pm00 = *(const uint2*)(aw_ + 0 * 32);                                     \
        pm01 = *(const uint2*)(aw_ + 1 * 32);                                     \
        pm02 = *(const uint2*)(aw_ + 2 * 32);                                     \
        pm03 = *(const uint2*)(aw_ + 3 * 32);                                     \
        pm10 = *(const uint2*)(aw_ + 16 * 32);                                    \
        pm11 = *(const uint2*)(aw_ + 17 * 32);                                    \
        pm12 = *(const uint2*)(aw_ + 18 * 32);                                    \
        pm13 = *(const uint2*)(aw_ + 19 * 32);                                    \
    } while (0)

#define ATTN_COMMIT() do {                                                        \
        *(uint4*)(KsP)            = kp0;                                          \
        *(uint4*)(KsP + 16 * 136) = kp1;                                          \
        *(uint4*)(KsP + 32 * 136) = kp2;                                          \
        *(uint4*)(KsP + 48 * 136) = kp3;                                          \
        *(uint4*)(VsP)            = vp0;                                          \
        *(uint4*)(VsP + 32 * 72)  = vp1;                                          \
        *(uint4*)(VsP + 64 * 72)  = vp2;                                          \
        *(uint4*)(VsP + 96 * 72)  = vp3;                                          \
    } while (0)

#define MASK_ROTATE() do {                                                        \
        cm00 = pm00; cm01 = pm01; cm02 = pm02; cm03 = pm03;                       \
        cm10 = pm10; cm11 = pm11; cm12 = pm12; cm13 = pm13;                       \
    } while (0)

    bf16x8 qf[2][4];
    #pragma unroll
    for (int mt = 0; mt < 2; mt++) {
        const bf16* qbase = Q + ((size_t)(b * N_ + n0 + mt * 16 + r)) * HSZ_ + h * 128;
        #pragma unroll
        for (int kc = 0; kc < 4; kc++) qf[mt][kc] = *(const bf16x8*)(qbase + kc * 32 + quad * 8);
    }

    f32x4 accv[2][8];
    #pragma unroll
    for (int mt = 0; mt < 2; mt++)
        #pragma unroll
        for (int dt = 0; dt < 8; dt++) accv[mt][dt] = (f32x4){0.f, 0.f, 0.f, 0.f};
    float tl[2][4] = {{0.f, 0.f, 0.f, 0.f}, {0.f, 0.f, 0.f, 0.f}};
    const float scale2 = 0.04419417382415922f * 1.4426950408889634f;  // scale*log2e
    const float SHIFT2 = 12.0f * 1.4426950408889634f;                 // cancels in P/l

    ATTN_ISSUE(0);
    for (int it = 0; it < 16; it++) {
        __syncthreads();               // all waves done reading Ks/Vs
        ATTN_COMMIT();                 // waits vmcnt for the prefetch set
        __syncthreads();               // staging visible
        MASK_ROTATE();                 // capture this iter's masks
        if (it + 1 < 16) ATTN_ISSUE(it + 1);   // K/V + masks fly under compute

        // QK^T: 4 groups of 16 keys; K-fragment shared by both m-tiles
        f32x4 cg[2][4];
        #pragma unroll
        for (int mt = 0; mt < 2; mt++)
            #pragma unroll
            for (int gk = 0; gk < 4; gk++) cg[mt][gk] = (f32x4){0.f, 0.f, 0.f, 0.f};
        __builtin_amdgcn_s_setprio(1);
        #pragma unroll
        for (int gk = 0; gk < 4; gk++)
            #pragma unroll
            for (int kc = 0; kc < 4; kc++) {
                bf16x8 kf = *(const bf16x8*)&Ks[gk * 16 + r][kc * 32 + quad * 8];
                cg[0][gk] = __builtin_amdgcn_mfma_f32_16x16x32_bf16(qf[0][kc], kf, cg[0][gk], 0, 0, 0);
                cg[1][gk] = __builtin_amdgcn_mfma_f32_16x16x32_bf16(qf[1][kc], kf, cg[1][gk], 0, 0, 0);
            }
        __builtin_amdgcn_s_setprio(0);

        // mask + exp2 -> plds + tl  (masks already in registers)
#define ATTN_SM(mt_, i_, cmx_) do {                                               \
            int row_l = (mt_) * 16 + quad * 4 + (i_);                             \
            unsigned wb0 = (cmx_).x, wb1 = (cmx_).y;                              \
            float p0 = ((wb0 >> r) & 1u)        ? exp2f(cg[mt_][0][i_] * scale2 - SHIFT2) : 0.f; \
            float p1 = ((wb0 >> (16 + r)) & 1u) ? exp2f(cg[mt_][1][i_] * scale2 - SHIFT2) : 0.f; \
            float p2 = ((wb1 >> r) & 1u)        ? exp2f(cg[mt_][2][i_] * scale2 - SHIFT2) : 0.f; \
            float p3 = ((wb1 >> (16 + r)) & 1u) ? exp2f(cg[mt_][3][i_] * scale2 - SHIFT2) : 0.f; \
            tl[mt_][i_] += p0 + p1 + p2 + p3;                                     \
            plds[w][row_l][r]      = (bf16)p0;                                    \
            plds[w][row_l][16 + r] = (bf16)p1;                                    \
            plds[w][row_l][32 + r] = (bf16)p2;                                    \
            plds[w][row_l][48 + r] = (bf16)p3;                                    \
        } while (0)
        ATTN_SM(0, 0, cm00); ATTN_SM(0, 1, cm01); ATTN_SM(0, 2, cm02); ATTN_SM(0, 3, cm03);
        ATTN_SM(1, 0, cm10); ATTN_SM(1, 1, cm11); ATTN_SM(1, 2, cm12); ATTN_SM(1, 3, cm13);
#undef ATTN_SM
        // no barrier: plds[w] is wave-private; same-wave DS ordering suffices

        // PV: P (A-op, 64 keys in 2 k-chunks) x Vs; V-fragments shared
        bf16x8 pf00 = *(const bf16x8*)&plds[w][r][quad * 8];
        bf16x8 pf01 = *(const bf16x8*)&plds[w][r][32 + quad * 8];
        bf16x8 pf10 = *(const bf16x8*)&plds[w][16 + r][quad * 8];
        bf16x8 pf11 = *(const bf16x8*)&plds[w][16 + r][32 + quad * 8];
        __builtin_amdgcn_s_setprio(1);
        #pragma unroll
        for (int dt = 0; dt < 8; dt++) {
            bf16x8 v0 = *(const bf16x8*)&Vs[dt * 16 + r][quad * 8];
            bf16x8 v1 = *(const bf16x8*)&Vs[dt * 16 + r][32 + quad * 8];
            accv[0][dt] = __builtin_amdgcn_mfma_f32_16x16x32_bf16(pf00, v0, accv[0][dt], 0, 0, 0);
            accv[0][dt] = __builtin_amdgcn_mfma_f32_16x16x32_bf16(pf01, v1, accv[0][dt], 0, 0, 0);
            accv[1][dt] = __builtin_amdgcn_mfma_f32_16x16x32_bf16(pf10, v0, accv[1][dt], 0, 0, 0);
            accv[1][dt] = __builtin_amdgcn_mfma_f32_16x16x32_bf16(pf11, v1, accv[1][dt], 0, 0, 0);
        }
        __builtin_amdgcn_s_setprio(0);
    }
#undef ATTN_ISSUE
#undef ATTN_COMMIT
#undef MASK_ROTATE

    // per-wave epilogue
    #pragma unroll
    for (int mt = 0; mt < 2; mt++)
        #pragma unroll
        for (int i = 0; i < 4; i++) {
            float l = tl[mt][i];
            #pragma unroll
            for (int d = 1; d < 16; d <<= 1) l += __shfl_xor(l, d, 64);
            float inv_l = 1.0f / fmaxf(l, 1e-30f);
            #pragma unroll
            for (int dt = 0; dt < 8; dt++) {
                int row = n0 + mt * 16 + quad * 4 + i;
                int col = h * 128 + dt * 16 + r;
                size_t idx = ((size_t)(b * N_ + row)) * HSZ_ + col;
                tpre[idx] = accv[mt][dt][i] * inv_l + (float)xb[idx];
            }
        }
}

// ---------------------------------------------------------------------------
// wave-per-row layernorm, 4 rows/block. OUT=0: bf16 to outB (intermediate).
// OUT=1: final lnorm2 of j=1 writes f32 directly to d_out (nodes + glob
// duplicate at n==E_); blocks >= 4096 fill node_mask with 1.0f.
template <int OUT>
__global__ __launch_bounds__(256) void lnorm_k(const float* __restrict__ in,
                                               const float* __restrict__ sc,
                                               const float* __restrict__ bi,
                                               bf16* __restrict__ outB,
                                               float* __restrict__ outF) {
    if (OUT == 1 && blockIdx.x >= 4096) {
        int idx = (blockIdx.x - 4096) * 1024 + threadIdx.x * 4;
        float4 one = {1.f, 1.f, 1.f, 1.f};
        *(float4*)&outF[(size_t)B_ * HSZ_ + (size_t)B_ * N_ * HSZ_ + idx] = one;
        return;
    }
    int row = blockIdx.x * 4 + (threadIdx.x >> 6);
    int lane = threadIdx.x & 63;
    const float* rp = in + (size_t)row * HSZ_;
    float4 a = *(const float4*)(rp + lane * 4);
    float4 b = *(const float4*)(rp + 256 + lane * 4);
    float sum = a.x + a.y + a.z + a.w + b.x + b.y + b.z + b.w;
    float sq  = a.x*a.x + a.y*a.y + a.z*a.z + a.w*a.w
              + b.x*b.x + b.y*b.y + b.z*b.z + b.w*b.w;
    #pragma unroll
    for (int d = 1; d < 64; d <<= 1) {
        sum += __shfl_xor(sum, d, 64);
        sq  += __shfl_xor(sq,  d, 64);
    }
    float mu = sum * (1.0f / HSZ_);
    float varv = fmaxf(sq * (1.0f / HSZ_) - mu * mu, 0.f);
    float rs = rsqrtf(varv + 1e-5f);
    int c0 = lane * 4;
    float va[4] = {a.x, a.y, a.z, a.w}, vb[4] = {b.x, b.y, b.z, b.w};
    if (OUT == 0) {
        bf16* op = outB + (size_t)row * HSZ_;
        #pragma unroll
        for (int k = 0; k < 4; k++) {
            op[c0 + k]       = (bf16)(((va[k] - mu) * rs) * sc[c0 + k] + bi[c0 + k]);
            op[c0 + 256 + k] = (bf16)(((vb[k] - mu) * rs) * sc[c0 + 256 + k] + bi[c0 + 256 + k]);
        }
    } else {
        float4 o1, o2;
        o1.x = ((va[0] - mu) * rs) * sc[c0 + 0] + bi[c0 + 0];
        o1.y = ((va[1] - mu) * rs) * sc[c0 + 1] + bi[c0 + 1];
        o1.z = ((va[2] - mu) * rs) * sc[c0 + 2] + bi[c0 + 2];
        o1.w = ((va[3] - mu) * rs) * sc[c0 + 3] + bi[c0 + 3];
        o2.x = ((vb[0] - mu) * rs) * sc[c0 + 256] + bi[c0 + 256];
        o2.y = ((vb[1] - mu) * rs) * sc[c0 + 257] + bi[c0 + 257];
        o2.z = ((vb[2] - mu) * rs) * sc[c0 + 258] + bi[c0 + 258];
        o2.w = ((vb[3] - mu) * rs) * sc[c0 + 259] + bi[c0 + 259];
        float* nodes = outF + (size_t)B_ * HSZ_;
        *(float4*)&nodes[(size_t)row * HSZ_ + c0]       = o1;
        *(float4*)&nodes[(size_t)row * HSZ_ + c0 + 256] = o2;
        int bb = row >> 10, n = row & 1023;
        if (n == E_) {
            *(float4*)&outF[(size_t)bb * HSZ_ + c0]       = o1;
            *(float4*)&outF[(size_t)bb * HSZ_ + c0 + 256] = o2;
        }
    }
}

// ---------------------------------------------------------------------------
extern "C" void kernel_launch(void* const* d_in, const int* in_sizes, int n_in,
                              void* d_out, int out_size, void* d_ws, size_t ws_size,
                              hipStream_t stream) {
    const float* ents = (const float*)d_in[0];
    const int*   rels = (const int*)d_in[1];
    const int*   adj  = (const int*)d_in[2];
    const float* renc = (const float*)d_in[3];
    const float* Wq   = (const float*)d_in[4];
    const float* Wk   = (const float*)d_in[5];
    const float* Wv   = (const float*)d_in[6];
    const float* l1w  = (const float*)d_in[7];
    const float* l1b  = (const float*)d_in[8];
    const float* l2w  = (const float*)d_in[9];
    const float* l2b  = (const float*)d_in[10];
    const float* ln1s = (const float*)d_in[11];
    const float* ln1b = (const float*)d_in[12];
    const float* ln2s = (const float*)d_in[13];
    const float* ln2b = (const float*)d_in[14];
    const float* pa   = (const float*)d_in[15];

    char* ws = (char*)d_ws;
    size_t o = 0;
    auto alloc = [&](size_t bytes) { void* p = ws + o; o += bytes; return p; };
    bf16*     WqkvT  = (bf16*)alloc(3145728);   // per j: 1536 rows x 512 (Wq|Wk|Wv)^T
    bf16*     L1T    = (bf16*)alloc(4194304);
    bf16*     L2T    = (bf16*)alloc(4194304);
    unsigned* adjw   = (unsigned*)alloc(2097152);
    bf16*     xb     = (bf16*)alloc(16777216);
    bf16*     Qb     = (bf16*)alloc(16777216);
    bf16*     Kb     = (bf16*)alloc(16777216);
    bf16*     Vt     = (bf16*)alloc(16777216);
    bf16*     tb     = (bf16*)alloc(16777216);
    bf16*     hb     = (bf16*)alloc(67108864);
    float*    f32buf = (float*)alloc(33554432);
    if (o > ws_size) return;

    prologue_k<<<26112, 256, 0, stream>>>(Wq, Wk, Wv, l1w, l2w, adj, ents, rels, renc,
                                          WqkvT, L1T, L2T, adjw, xb);

    for (int j = 0; j < 2; j++) {
        gemm_bt<4><<<dim3(12, 128), 256, 0, stream>>>(xb, WqkvT + j * 786432, nullptr, nullptr, nullptr,
                                                      Qb, Kb, Vt, nullptr, 1536, 512);
        attn_fused<<<512, 256, 0, stream>>>(Qb, Kb, Vt, adjw, xb, f32buf);
        lnorm_k<0><<<4096, 256, 0, stream>>>(f32buf, ln1s + j * 512, ln1b + j * 512, tb, nullptr);
        gemm_bt<2><<<dim3(16, 128), 256, 0, stream>>>(tb, L1T + j * 1048576, l1b + j * 2048, pa + j * 2048,
                                                      nullptr, hb, nullptr, nullptr, nullptr, 2048, 512);
        gemm_bt<3><<<dim3(4, 128), 256, 0, stream>>>(hb, L2T + j * 1048576, l2b + j * 512, nullptr,
                                                     tb, nullptr, nullptr, nullptr, f32buf, 512, 2048);
        if (j == 0)
            lnorm_k<0><<<4096, 256, 0, stream>>>(f32buf, ln2s, ln2b, xb, nullptr);
        else
            lnorm_k<1><<<4112, 256, 0, stream>>>(f32buf, ln2s + 512, ln2b + 512, nullptr, (float*)d_out);
    }
}